// Round 8
// baseline (1105.402 us; speedup 1.0000x reference)
//
#include <hip/hip_runtime.h>
#include <math.h>

#define T_STEPS 8
#define NNODES 10000
#define NFEAT 16
#define NEDGES 320000
#define HDIM 64
#define LDIM 3
#define CAP 128
#define NPW 8                   // nodes per wave in k_node_update

typedef _Float16 f16x8 __attribute__((ext_vector_type(8)));
typedef float f32x4 __attribute__((ext_vector_type(4)));

__device__ __forceinline__ float sigmoidf_(float x){ return 1.f/(1.f+__expf(-x)); }
__device__ __forceinline__ float softplusf_(float x){ return fmaxf(x,0.f)+log1pf(__expf(-fabsf(x))); }
__device__ __forceinline__ float tanhf_(float x){ return 2.f*sigmoidf_(2.f*x)-1.f; }

// ---------------- setup kernels (once per call) ----------------

// Collapse ee-layer2 + attention-layer1(ef half) into fp16 hi/lo MFMA B-fragments.
__global__ void __launch_bounds__(256) k_prep(
    const float* __restrict__ ee_w2, const float* __restrict__ ee_b2,
    const float* __restrict__ at_w1, const float* __restrict__ at_b1,
    _Float16* __restrict__ P_Mhi, _Float16* __restrict__ P_Mlo,
    float* __restrict__ cvec)
{
    int i = blockIdx.x*256 + threadIdx.x;   // 0..4095
    if (i >= 64*64) return;
    int m = i>>6, j = i&63;                 // m = K index, j = output col
    float acc = 0.f;
    #pragma unroll 8
    for (int k=0;k<64;++k) acc += ee_w2[k*64+m]*at_w1[j*128+k];
    int ks = m>>5;
    int lane = ((m>>3)&3)*16 + (j&15);
    int elem = m&7;
    int fi = (j>>4)*2 + ks;
    _Float16 hi = (_Float16)acc;
    P_Mhi[(fi*64+lane)*8+elem] = hi;
    P_Mlo[(fi*64+lane)*8+elem] = (_Float16)(acc - (float)hi);
    if (m == 0){
        float c = at_b1[j];
        #pragma unroll 8
        for (int k=0;k<64;++k) c += ee_b2[k]*at_w1[j*128+k];
        cvec[j] = c;
    }
}

// init state + pack weights LANE-MAJOR for coalesced per-wave direct-L2 reads:
// P_wih[((k4*3+g)*64+j)*4+kk] ; P_whh same (16 k4) ; P_en/P_de/P_a2 [(k4*64+j)*4+kk]
__global__ void __launch_bounds__(256) k_init(
    const float* __restrict__ init_lice, const float* __restrict__ cvec,
    const float* __restrict__ gru_wih, const float* __restrict__ gru_whh,
    const float* __restrict__ en_w2, const float* __restrict__ de_w1,
    const float* __restrict__ at_w1,
    float* __restrict__ h, float* __restrict__ lice, float* __restrict__ G,
    float* __restrict__ P_en, float* __restrict__ P_wih, float* __restrict__ P_whh,
    float* __restrict__ P_de, float* __restrict__ P_a2,
    int* __restrict__ counts)
{
    int i = blockIdx.x*256 + threadIdx.x;              // 0 .. 639999
    if (i < NNODES*HDIM){ h[i] = 0.f; G[i] = cvec[i&63]; }
    if (i < NNODES*LDIM) lice[i] = init_lice[i];
    if (i < NNODES) counts[i] = 0;
    if (i < 13824){                                   // lane-major ih
        int kk = i&3, t = i>>2, j = t&63, u = t>>6;   // u 0..53
        int g = u%3, k4 = u/3;
        P_wih[i] = gru_wih[(g*64+j)*72 + 4*k4 + kk];
    }
    if (i < 12288){                                   // lane-major hh
        int kk = i&3, t = i>>2, j = t&63, u = t>>6;   // u 0..47
        int g = u%3, k4 = u/3;
        P_whh[i] = gru_whh[(g*64+j)*64 + 4*k4 + kk];
    }
    if (i < 4096){
        int k4 = i>>8, r = i&255, j = r>>2, kk = r&3;
        P_en[i] = en_w2[j*64 + 4*k4 + kk];
        P_de[i] = de_w1[j*64 + 4*k4 + kk];
        P_a2[i] = at_w1[j*128 + 64 + 4*k4 + kk];
    }
}

// fec depends only on temp -> precompute for all (t,n)
__global__ void __launch_bounds__(256) k_fec(
    const float* __restrict__ nfs,
    const float* __restrict__ fe_w1, const float* __restrict__ fe_b1,
    const float* __restrict__ fe_w2, const float* __restrict__ fe_b2,
    const float* __restrict__ fe_w3, const float* __restrict__ fe_b3,
    float* __restrict__ fec_arr)
{
    int i = blockIdx.x*256 + threadIdx.x;
    if (i >= T_STEPS*NNODES) return;
    float temp = nfs[(size_t)i*NFEAT + 11];
    float tn = (temp - 10.f)*(1.f/5.f);
    float a[32];
    #pragma unroll
    for (int k=0;k<32;++k) a[k] = fmaxf(tn*fe_w1[k] + fe_b1[k], 0.f);
    float o = fe_b3[0];
    #pragma unroll 4
    for (int l=0;l<32;++l){
        float b = fe_b2[l];
        #pragma unroll
        for (int k=0;k<32;++k) b += a[k]*fe_w2[l*32+k];
        o += fmaxf(b, 0.f)*fe_w3[l];
    }
    fec_arr[i] = softplusf_(o);
}

__global__ void __launch_bounds__(256) k_hist(const int* __restrict__ ei_dst, int* __restrict__ counts){
    int e = blockIdx.x*256 + threadIdx.x;
    if (e < NEDGES) atomicAdd(&counts[ei_dst[e]], 1);
}

__global__ void __launch_bounds__(1024) k_scan(const int* __restrict__ counts,
                                               int* __restrict__ rowptr, int* __restrict__ cursor){
    __shared__ int sums[1024];
    int t = threadIdx.x;
    const int CH = 10;
    int c0 = t*CH;
    int s = 0;
    if (c0 < NNODES){
        #pragma unroll
        for (int i=0;i<CH;i++) s += counts[c0+i];
    }
    sums[t] = s;
    __syncthreads();
    for (int off=1; off<1024; off<<=1){
        int v = (t>=off) ? sums[t-off] : 0;
        __syncthreads();
        sums[t] += v;
        __syncthreads();
    }
    if (c0 < NNODES){
        int run = (t==0) ? 0 : sums[t-1];
        for (int i=0;i<CH;i++){ rowptr[c0+i] = run; run += counts[c0+i]; cursor[c0+i] = 0; }
        if (t == (NNODES/CH)-1) rowptr[NNODES] = run;
    }
}

__global__ void __launch_bounds__(256) k_scatter(const int* __restrict__ ei_dst,
        const int* __restrict__ rowptr, int* __restrict__ cursor, int* __restrict__ perm){
    int e = blockIdx.x*256 + threadIdx.x;
    if (e >= NEDGES) return;
    int d = ei_dst[e];
    int pos = rowptr[d] + atomicAdd(&cursor[d], 1);
    perm[pos] = e;
}

// pre-gather step-invariant per-edge data into CSR (perm) order
__global__ void __launch_bounds__(256) k_permg(
    const int* __restrict__ perm, const int* __restrict__ ei_src,
    const float* __restrict__ dist, const float* __restrict__ dirn,
    int* __restrict__ src_perm, float* __restrict__ dist_p, float* __restrict__ dirn_p)
{
    int i = blockIdx.x*256 + threadIdx.x;
    if (i >= NEDGES) return;
    int e = perm[i];
    src_perm[i] = ei_src[e];
    dist_p[i] = dist[e];
    float2 dd = *reinterpret_cast<const float2*>(dirn + 2*e);
    *reinterpret_cast<float2*>(dirn_p + 2*i) = dd;
}

// ---------------- per-step kernel 1: edge MLPs -> logits (MFMA fp16x3) ----------------

__global__ void __launch_bounds__(256,2) k_edge_mfma(
    const float* __restrict__ xt, const float* __restrict__ G,
    const int* __restrict__ src_perm,
    const float* __restrict__ dist_p, const float* __restrict__ dirn_p,
    const float* __restrict__ ee_w1, const float* __restrict__ ee_b1,
    const _Float16* __restrict__ P_Mhi, const _Float16* __restrict__ P_Mlo,
    const float* __restrict__ at_w2, const float* __restrict__ at_b2,
    float* __restrict__ logits)
{
    __shared__ __align__(16) _Float16 smh[36864];   // A_hi [256][72] | A_lo [256][72]; reused for C
    float* smf = (float*)smh;

    const int tid = threadIdx.x;
    const int wv = tid>>6, lane = tid&63;
    const int e = blockIdx.x*256 + tid;

    // B fragments (M_hi/M_lo), coalesced 16B/lane loads
    f16x8 bh[4][2], bl[4][2];
    #pragma unroll
    for (int jt=0;jt<4;++jt){
        #pragma unroll
        for (int ks=0;ks<2;++ks){
            bh[jt][ks] = *(const f16x8*)(P_Mhi + (((jt*2+ks)*64 + lane)*8));
            bl[jt][ks] = *(const f16x8*)(P_Mlo + (((jt*2+ks)*64 + lane)*8));
        }
    }

    // ---- phase 1: per-edge features + relu(h1) -> LDS hi/lo ----
    const int src = src_perm[e];
    const float d  = dist_p[e];
    float2 dir2 = *reinterpret_cast<const float2*>(dirn_p + 2*e);
    float temp = xt[src*NFEAT+11];
    float4 q  = *reinterpret_cast<const float4*>(xt + src*NFEAT + 12); // sal,u,v,pad
    float flux = q.y*dir2.x + q.z*dir2.y;
    float wflux = fmaxf(flux, 0.f) * __expf(-d*(1.f/15.f));
    const float a0 = d, a1 = wflux, a2 = temp, a3 = q.x;
    const float lbias = at_b2[0] + __logf(wflux + 1e-8f);

    #pragma unroll
    for (int kb=0;kb<8;++kb){
        f16x8 hv, lv;
        #pragma unroll
        for (int i=0;i<8;++i){
            const int m = kb*8+i;
            float4 w1 = *reinterpret_cast<const float4*>(ee_w1 + m*4);  // uniform -> s_load
            float r = fmaxf(ee_b1[m] + a0*w1.x + a1*w1.y + a2*w1.z + a3*w1.w, 0.f);
            _Float16 hi = (_Float16)r;
            hv[i] = hi;
            lv[i] = (_Float16)(r - (float)hi);
        }
        *(f16x8*)(smh + tid*72 + kb*8)         = hv;
        *(f16x8*)(smh + 18432 + tid*72 + kb*8) = lv;
    }
    asm volatile("s_waitcnt lgkmcnt(0)" ::: "memory");

    // ---- phase 2: wave-local MFMA GEMM ----
    f32x4 c[4][4];
    #pragma unroll
    for (int et=0;et<4;++et)
        #pragma unroll
        for (int jt=0;jt<4;++jt)
            c[et][jt] = (f32x4){0.f,0.f,0.f,0.f};

    #pragma unroll
    for (int et=0;et<4;++et){
        #pragma unroll
        for (int ks=0;ks<2;++ks){
            const int row = wv*64 + et*16 + (lane&15);
            f16x8 ah = *(const f16x8*)(smh + row*72 + ks*32 + (lane>>4)*8);
            f16x8 al = *(const f16x8*)(smh + 18432 + row*72 + ks*32 + (lane>>4)*8);
            #pragma unroll
            for (int jt=0;jt<4;++jt){
                c[et][jt] = __builtin_amdgcn_mfma_f32_16x16x32_f16(ah, bh[jt][ks], c[et][jt], 0,0,0);
                c[et][jt] = __builtin_amdgcn_mfma_f32_16x16x32_f16(ah, bl[jt][ks], c[et][jt], 0,0,0);
                c[et][jt] = __builtin_amdgcn_mfma_f32_16x16x32_f16(al, bh[jt][ks], c[et][jt], 0,0,0);
            }
        }
    }
    asm volatile("s_waitcnt lgkmcnt(0)" ::: "memory");

    // ---- C -> LDS (re-use this wave's own A region) ----
    #pragma unroll
    for (int et=0;et<4;++et){
        #pragma unroll
        for (int jt=0;jt<4;++jt){
            #pragma unroll
            for (int i=0;i<4;++i){
                const int rl = et*16 + ((lane>>4)&3)*4 + i;
                const int col = jt*16 + (lane&15);
                const int idx = (et < 2) ? (wv*2304 + rl*68 + col)
                                         : (9216 + wv*2304 + (rl-32)*68 + col);
                smf[idx] = c[et][jt][i];
            }
        }
    }
    asm volatile("s_waitcnt lgkmcnt(0)" ::: "memory");

    // ---- phase 3: epilogue, thread-per-edge ----
    const int el = tid & 63;
    const float* crow = smf + ((el < 32) ? (wv*2304 + el*68)
                                         : (9216 + wv*2304 + (el-32)*68));
    const float4* G4 = reinterpret_cast<const float4*>(G + src*HDIM);
    float logit = lbias;
    #pragma unroll
    for (int jj=0;jj<16;++jj){
        float4 cv = *reinterpret_cast<const float4*>(crow + jj*4);
        float4 gv = G4[jj];
        float4 w4 = *reinterpret_cast<const float4*>(at_w2 + jj*4);   // uniform -> s_load
        logit += w4.x*fmaxf(cv.x+gv.x,0.f) + w4.y*fmaxf(cv.y+gv.y,0.f)
               + w4.z*fmaxf(cv.z+gv.z,0.f) + w4.w*fmaxf(cv.w+gv.w,0.f);
    }
    logits[e] = logit;
}

// ---------------- per-step kernel 2: segment softmax + pressure ----------------

__global__ void __launch_bounds__(256) k_softmax_pressure(
    const float* __restrict__ logits, const float* __restrict__ h,
    const float* __restrict__ lice, const int* __restrict__ src_perm,
    const int* __restrict__ rowptr,
    const float* __restrict__ log_beta,
    float* __restrict__ pressure)
{
    __shared__ float swgt[CAP];
    __shared__ int   ssrc[CAP];
    __shared__ float sred[4][64];
    __shared__ float sredm[4], sreds[4];

    const int node = blockIdx.x;
    const int tid = threadIdx.x;
    const int wid = tid >> 6;
    const int lane = tid & 63;
    const int start = rowptr[node], end = rowptr[node+1];
    const int deg = end - start;
    const int nfast = deg < CAP ? deg : CAP;

    float m = -INFINITY;
    for (int i=start+tid; i<end; i+=256){
        float lg = logits[i];
        int o = i - start;
        if (o < CAP){ swgt[o] = lg; ssrc[o] = src_perm[i]; }
        m = fmaxf(m, lg);
    }
    #pragma unroll
    for (int off=32; off>=1; off>>=1) m = fmaxf(m, __shfl_xor(m, off));
    if (lane == 0) sredm[wid] = m;
    __syncthreads();
    m = fmaxf(fmaxf(sredm[0], sredm[1]), fmaxf(sredm[2], sredm[3]));

    float s = 0.f;
    for (int i=start+tid; i<end; i+=256){
        int o = i - start;
        float lg = (o < CAP) ? swgt[o] : logits[i];
        s += __expf(lg - m);
    }
    #pragma unroll
    for (int off=32; off>=1; off>>=1) s += __shfl_xor(s, off);
    if (lane == 0) sreds[wid] = s;
    __syncthreads();
    s = (sreds[0]+sreds[1])+(sreds[2]+sreds[3]);

    const float binv = __expf(log_beta[0])/(s + 1e-8f);

    for (int o=tid; o<nfast; o+=256){
        int sc = ssrc[o];
        swgt[o] = __expf(swgt[o] - m) * binv * lice[sc*LDIM];
    }
    __syncthreads();

    float p = 0.f;
    for (int o=wid; o<nfast; o+=4)
        p += swgt[o]*h[ssrc[o]*HDIM + lane];
    for (int i=start+CAP+wid; i<end; i+=4){
        int sc = src_perm[i];
        float wg = __expf(logits[i]-m)*binv*lice[sc*LDIM];
        p += wg*h[sc*HDIM+lane];
    }
    sred[wid][lane] = p;
    __syncthreads();
    if (wid == 0)
        pressure[node*HDIM + lane] = (sred[0][lane]+sred[1][lane])+(sred[2][lane]+sred[3][lane]);
}

// ---------------- per-step kernel 3: node update + G projection ----------------
// One WAVE per block, NPW=8 nodes/wave, ZERO barriers. Weights direct from L2
// (lane-major packed -> coalesced dwordx4); each weight load feeds 8 nodes' FMAs.
// Input vectors broadcast via wave-local LDS (same-address reads = free).

__global__ void __launch_bounds__(64,1) k_node_update(
    const float* __restrict__ xt,
    float* __restrict__ h, float* __restrict__ lice,
    const float* __restrict__ pressure,
    const float* __restrict__ en_w1, const float* __restrict__ en_b1, const float* __restrict__ en_b2,
    const float* __restrict__ P_en, const float* __restrict__ P_wih, const float* __restrict__ P_whh,
    const float* __restrict__ P_de, const float* __restrict__ P_a2,
    const float* __restrict__ gru_bih, const float* __restrict__ gru_bhh,
    const float* __restrict__ de_b1, const float* __restrict__ de_w2, const float* __restrict__ de_b2,
    const float* __restrict__ cvec, const float* __restrict__ fec_t,
    const float* __restrict__ temp_sens,
    float* __restrict__ G, float* __restrict__ out_t)
{
    __shared__ float s_din[NPW][76];
    __shared__ float s_h[NPW][64];
    __shared__ float s_x[NPW][64];

    const int lane = threadIdx.x;          // one wave
    const int nb = blockIdx.x*NPW;

    // ---- gather per-node state (same-wave LDS: in-order, no barrier) ----
    float hv[NPW], pm[NPW];
    #pragma unroll
    for (int m=0;m<NPW;++m){
        const int n = nb+m;
        hv[m] = h[n*HDIM+lane];
        s_h[m][lane] = hv[m];
        pm[m] = pressure[n*HDIM+lane];
        if (lane < 5)      s_din[m][64+lane] = xt[n*NFEAT+11+lane];
        else if (lane < 8) s_din[m][64+lane] = lice[n*LDIM + (lane-5)];
    }

    // ---- enc1 (5->64, relu) ----
    #pragma unroll
    for (int m=0;m<NPW;++m){
        float t1 = en_b1[lane];
        #pragma unroll
        for (int k=0;k<5;++k) t1 += s_din[m][64+k]*en_w1[lane*5+k];
        s_x[m][lane] = fmaxf(t1, 0.f);
    }

    // ---- enc2 (64->64) + pressure -> din ----
    float dinl[NPW];
    #pragma unroll
    for (int m=0;m<NPW;++m) dinl[m] = en_b2[lane] + pm[m];
    #pragma unroll 4
    for (int k4=0;k4<16;++k4){
        float4 w4 = *reinterpret_cast<const float4*>(P_en + (k4*64+lane)*4);
        #pragma unroll
        for (int m=0;m<NPW;++m){
            float4 x4 = *reinterpret_cast<const float4*>(&s_x[m][k4*4]);
            dinl[m] += x4.x*w4.x + x4.y*w4.y + x4.z*w4.z + x4.w*w4.w;
        }
    }
    #pragma unroll
    for (int m=0;m<NPW;++m) s_din[m][lane] = dinl[m];

    // ---- GRU input side (18 k4, direct L2; each load feeds 8 nodes) ----
    float gi0[NPW], gi1[NPW], gi2[NPW];
    #pragma unroll
    for (int m=0;m<NPW;++m){
        gi0[m]=gru_bih[lane]; gi1[m]=gru_bih[64+lane]; gi2[m]=gru_bih[128+lane];
    }
    #pragma unroll 3
    for (int k4=0;k4<18;++k4){
        float4 w0 = *reinterpret_cast<const float4*>(P_wih + ((k4*3+0)*64+lane)*4);
        float4 w1 = *reinterpret_cast<const float4*>(P_wih + ((k4*3+1)*64+lane)*4);
        float4 w2 = *reinterpret_cast<const float4*>(P_wih + ((k4*3+2)*64+lane)*4);
        #pragma unroll
        for (int m=0;m<NPW;++m){
            float4 x4 = *reinterpret_cast<const float4*>(&s_din[m][k4*4]);
            gi0[m] += x4.x*w0.x + x4.y*w0.y + x4.z*w0.z + x4.w*w0.w;
            gi1[m] += x4.x*w1.x + x4.y*w1.y + x4.z*w1.z + x4.w*w1.w;
            gi2[m] += x4.x*w2.x + x4.y*w2.y + x4.z*w2.z + x4.w*w2.w;
        }
    }

    // ---- GRU hidden side (16 k4, direct L2) ----
    float gh0[NPW], gh1[NPW], gh2[NPW];
    #pragma unroll
    for (int m=0;m<NPW;++m){
        gh0[m]=gru_bhh[lane]; gh1[m]=gru_bhh[64+lane]; gh2[m]=gru_bhh[128+lane];
    }
    #pragma unroll 4
    for (int k4=0;k4<16;++k4){
        float4 w0 = *reinterpret_cast<const float4*>(P_whh + ((k4*3+0)*64+lane)*4);
        float4 w1 = *reinterpret_cast<const float4*>(P_whh + ((k4*3+1)*64+lane)*4);
        float4 w2 = *reinterpret_cast<const float4*>(P_whh + ((k4*3+2)*64+lane)*4);
        #pragma unroll
        for (int m=0;m<NPW;++m){
            float4 x4 = *reinterpret_cast<const float4*>(&s_h[m][k4*4]);
            gh0[m] += x4.x*w0.x + x4.y*w0.y + x4.z*w0.z + x4.w*w0.w;
            gh1[m] += x4.x*w1.x + x4.y*w1.y + x4.z*w1.z + x4.w*w1.w;
            gh2[m] += x4.x*w2.x + x4.y*w2.y + x4.z*w2.z + x4.w*w2.w;
        }
    }

    // ---- GRU glue; write hnew (global + in-place s_h, same-wave) ----
    #pragma unroll
    for (int m=0;m<NPW;++m){
        const int n = nb+m;
        float r  = sigmoidf_(gi0[m] + gh0[m]);
        float z  = sigmoidf_(gi1[m] + gh1[m]);
        float nn = tanhf_(gi2[m] + r*gh2[m]);
        float hnew = (1.f - z)*nn + z*hv[m];
        h[n*HDIM+lane] = hnew;
        s_h[m][lane] = hnew;
    }

    // ---- dec1 (64->64 relu) and G projection (cvec + hnew @ A2) ----
    float d1m[NPW], gv[NPW];
    #pragma unroll
    for (int m=0;m<NPW;++m){ d1m[m] = de_b1[lane]; gv[m] = cvec[lane]; }
    #pragma unroll 4
    for (int k4=0;k4<16;++k4){
        float4 wd = *reinterpret_cast<const float4*>(P_de + (k4*64+lane)*4);
        float4 wa = *reinterpret_cast<const float4*>(P_a2 + (k4*64+lane)*4);
        #pragma unroll
        for (int m=0;m<NPW;++m){
            float4 x4 = *reinterpret_cast<const float4*>(&s_h[m][k4*4]);
            d1m[m] += x4.x*wd.x + x4.y*wd.y + x4.z*wd.z + x4.w*wd.w;
            gv[m]  += x4.x*wa.x + x4.y*wa.y + x4.z*wa.z + x4.w*wa.w;
        }
    }
    #pragma unroll
    for (int m=0;m<NPW;++m){
        const int n = nb+m;
        G[n*HDIM+lane] = gv[m];
        d1m[m] = fmaxf(d1m[m], 0.f);
    }

    // ---- dec2 (64->3) via shuffle reduce, then output ----
    #pragma unroll
    for (int m=0;m<NPW;++m){
        const int n = nb+m;
        float s0 = d1m[m]*de_w2[lane];
        float s1 = d1m[m]*de_w2[64+lane];
        float s2 = d1m[m]*de_w2[128+lane];
        #pragma unroll
        for (int off=32; off>=1; off>>=1){
            s0 += __shfl_xor(s0, off);
            s1 += __shfl_xor(s1, off);
            s2 += __shfl_xor(s2, off);
        }
        float fec = fec_t[n];
        if (lane < LDIM){
            float oi = (lane==0 ? s0 : (lane==1 ? s1 : s2)) + de_b2[lane];
            float lb = softplusf_(oi);
            float ln = lb * (1.f + temp_sens[0]*(fec - 1.f));
            lice[n*LDIM+lane] = ln;
            out_t[n*LDIM+lane] = ln;
        }
    }
}

// ---------------- launcher ----------------

extern "C" void kernel_launch(void* const* d_in, const int* in_sizes, int n_in,
                              void* d_out, int out_size, void* d_ws, size_t ws_size,
                              hipStream_t stream) {
    const float* nfs       = (const float*)d_in[0];
    const float* init_lice = (const float*)d_in[1];
    const float* dist      = (const float*)d_in[2];
    const float* dirn      = (const float*)d_in[3];
    const float* ee_w1     = (const float*)d_in[4];
    const float* ee_b1     = (const float*)d_in[5];
    const float* ee_w2     = (const float*)d_in[6];
    const float* ee_b2     = (const float*)d_in[7];
    const float* at_w1     = (const float*)d_in[8];
    const float* at_b1     = (const float*)d_in[9];
    const float* at_w2     = (const float*)d_in[10];
    const float* at_b2     = (const float*)d_in[11];
    const float* en_w1     = (const float*)d_in[12];
    const float* en_b1     = (const float*)d_in[13];
    const float* en_w2     = (const float*)d_in[14];
    const float* en_b2     = (const float*)d_in[15];
    const float* fe_w1     = (const float*)d_in[16];
    const float* fe_b1     = (const float*)d_in[17];
    const float* fe_w2     = (const float*)d_in[18];
    const float* fe_b2     = (const float*)d_in[19];
    const float* fe_w3     = (const float*)d_in[20];
    const float* fe_b3     = (const float*)d_in[21];
    const float* gru_wih   = (const float*)d_in[22];
    const float* gru_whh   = (const float*)d_in[23];
    const float* gru_bih   = (const float*)d_in[24];
    const float* gru_bhh   = (const float*)d_in[25];
    const float* de_w1     = (const float*)d_in[26];
    const float* de_b1     = (const float*)d_in[27];
    const float* de_w2     = (const float*)d_in[28];
    const float* de_b2     = (const float*)d_in[29];
    const float* log_beta  = (const float*)d_in[30];
    const float* temp_sens = (const float*)d_in[31];
    const int*   ei        = (const int*)d_in[32];
    const int*   ei_src = ei;
    const int*   ei_dst = ei + NEDGES;
    float* out = (float*)d_out;

    // workspace carve (floats; keep offsets %4 for 16B alignment)
    float* wsf = (float*)d_ws;
    size_t off = 0;
    float* h        = wsf + off; off += (size_t)NNODES*HDIM;   // 640000
    float* lice     = wsf + off; off += (size_t)NNODES*LDIM + 2;
    off = (off + 3) & ~(size_t)3;
    float* logits   = wsf + off; off += (size_t)NEDGES;        // 320000
    float* pressure = wsf + off; off += (size_t)NNODES*HDIM;   // 640000
    float* G        = wsf + off; off += (size_t)NNODES*HDIM;   // 640000
    float* cvec     = wsf + off; off += 64;
    _Float16* P_Mhi = (_Float16*)(wsf + off); off += 2048;     // 4096 halves
    _Float16* P_Mlo = (_Float16*)(wsf + off); off += 2048;
    float* P_en     = wsf + off; off += 4096;
    float* P_wih    = wsf + off; off += 13824;
    float* P_whh    = wsf + off; off += 12288;
    float* P_de     = wsf + off; off += 4096;
    float* P_a2     = wsf + off; off += 4096;
    float* fec_arr  = wsf + off; off += (size_t)T_STEPS*NNODES; // 80000
    float* dist_p   = wsf + off; off += NEDGES;                // 320000
    float* dirn_p   = wsf + off; off += 2*NEDGES;              // 640000
    int* src_perm = (int*)(wsf + off); off += NEDGES;
    int* counts = (int*)(wsf + off); off += NNODES;
    int* rowptr = (int*)(wsf + off); off += NNODES+1;
    int* cursor = (int*)(wsf + off); off += NNODES;
    int* perm   = (int*)(wsf + off); off += NEDGES;

    // setup (k_prep first: k_init consumes cvec)
    k_prep<<<16,256,0,stream>>>(ee_w2, ee_b2, at_w1, at_b1, P_Mhi, P_Mlo, cvec);
    k_init<<<2500,256,0,stream>>>(init_lice, cvec, gru_wih, gru_whh, en_w2, de_w1, at_w1,
                                  h, lice, G, P_en, P_wih, P_whh, P_de, P_a2, counts);
    k_fec<<<(T_STEPS*NNODES+255)/256,256,0,stream>>>(nfs, fe_w1, fe_b1, fe_w2, fe_b2,
                                                     fe_w3, fe_b3, fec_arr);
    k_hist<<<1250,256,0,stream>>>(ei_dst, counts);
    k_scan<<<1,1024,0,stream>>>(counts, rowptr, cursor);
    k_scatter<<<1250,256,0,stream>>>(ei_dst, rowptr, cursor, perm);
    k_permg<<<1250,256,0,stream>>>(perm, ei_src, dist, dirn, src_perm, dist_p, dirn_p);

    for (int t=0; t<T_STEPS; ++t){
        const float* xt = nfs + (size_t)t*NNODES*NFEAT;
        k_edge_mfma<<<1250,256,0,stream>>>(xt, G, src_perm, dist_p, dirn_p,
                                           ee_w1, ee_b1, P_Mhi, P_Mlo,
                                           at_w2, at_b2, logits);
        k_softmax_pressure<<<NNODES,256,0,stream>>>(logits, h, lice, src_perm,
                                                    rowptr, log_beta, pressure);
        k_node_update<<<NNODES/NPW,64,0,stream>>>(xt, h, lice, pressure,
                                             en_w1, en_b1, en_b2,
                                             P_en, P_wih, P_whh, P_de, P_a2,
                                             gru_bih, gru_bhh,
                                             de_b1, de_w2, de_b2,
                                             cvec, fec_arr + (size_t)t*NNODES,
                                             temp_sens,
                                             G, out + (size_t)t*NNODES*LDIM);
    }
}

// Round 9
// 834.950 us; speedup vs baseline: 1.3239x; 1.3239x over previous
//
#include <hip/hip_runtime.h>
#include <math.h>

#define T_STEPS 8
#define NNODES 10000
#define NFEAT 16
#define NEDGES 320000
#define HDIM 64
#define LDIM 3
#define CAP 128

typedef _Float16 f16x8 __attribute__((ext_vector_type(8)));
typedef _Float16 f16x4 __attribute__((ext_vector_type(4)));
typedef float f32x4 __attribute__((ext_vector_type(4)));

__device__ __forceinline__ float sigmoidf_(float x){ return 1.f/(1.f+__expf(-x)); }
__device__ __forceinline__ float softplusf_(float x){ return fmaxf(x,0.f)+log1pf(__expf(-fabsf(x))); }
__device__ __forceinline__ float tanhf_(float x){ return 2.f*sigmoidf_(2.f*x)-1.f; }

// ---------------- setup kernels (once per call) ----------------

// Collapse ee-layer2 + attention-layer1(ef half) into fp16 hi/lo MFMA B-fragments (for edge kernel).
__global__ void __launch_bounds__(256) k_prep(
    const float* __restrict__ ee_w2, const float* __restrict__ ee_b2,
    const float* __restrict__ at_w1, const float* __restrict__ at_b1,
    _Float16* __restrict__ P_Mhi, _Float16* __restrict__ P_Mlo,
    float* __restrict__ cvec)
{
    int i = blockIdx.x*256 + threadIdx.x;   // 0..4095
    if (i >= 64*64) return;
    int m = i>>6, j = i&63;                 // m = K index, j = output col
    float acc = 0.f;
    #pragma unroll 8
    for (int k=0;k<64;++k) acc += ee_w2[k*64+m]*at_w1[j*128+k];
    int ks = m>>5;
    int lane = ((m>>3)&3)*16 + (j&15);
    int elem = m&7;
    int fi = (j>>4)*2 + ks;
    _Float16 hi = (_Float16)acc;
    P_Mhi[(fi*64+lane)*8+elem] = hi;
    P_Mlo[(fi*64+lane)*8+elem] = (_Float16)(acc - (float)hi);
    if (m == 0){
        float c = at_b1[j];
        #pragma unroll 8
        for (int k=0;k<64;++k) c += ee_b2[k]*at_w1[j*128+k];
        cvec[j] = c;
    }
}

// Generic B-fragment packer: B[k][j] taken from W[j*ldw + koff + k], zero for k>=K.
// Fragment element li: elem=li&7, lane=(li>>3)&63, fi=li>>9; jt=fi/NKS, ks=fi%NKS;
// j = jt*16+(lane&15), k = ks*32+((lane>>4)&3)*8+elem.
__device__ __forceinline__ void packB(const float* __restrict__ W, int ldw, int koff, int K, int NKS,
                                      _Float16* __restrict__ Dhi, _Float16* __restrict__ Dlo, int li){
    int elem = li & 7;
    int lane = (li >> 3) & 63;
    int fi   = li >> 9;
    int jt = fi / NKS, ks = fi % NKS;
    int j = jt*16 + (lane & 15);
    int k = ks*32 + ((lane>>4)&3)*8 + elem;
    float v = (k < K) ? W[j*ldw + koff + k] : 0.f;
    _Float16 hi = (_Float16)v;
    Dhi[li] = hi;
    Dlo[li] = (_Float16)(v - (float)hi);
}

// init state + pack node-update weights into MFMA B-fragments
__global__ void __launch_bounds__(256) k_init(
    const float* __restrict__ init_lice, const float* __restrict__ cvec,
    const float* __restrict__ en_w1, const float* __restrict__ en_w2,
    const float* __restrict__ gru_wih, const float* __restrict__ gru_whh,
    const float* __restrict__ de_w1, const float* __restrict__ at_w1,
    float* __restrict__ h, float* __restrict__ lice, float* __restrict__ G,
    _Float16* __restrict__ F_en1h, _Float16* __restrict__ F_en1l,
    _Float16* __restrict__ F_enh,  _Float16* __restrict__ F_enl,
    _Float16* __restrict__ F_ihh,  _Float16* __restrict__ F_ihl,
    _Float16* __restrict__ F_hhh,  _Float16* __restrict__ F_hhl,
    _Float16* __restrict__ F_deh,  _Float16* __restrict__ F_del,
    _Float16* __restrict__ F_a2h,  _Float16* __restrict__ F_a2l,
    int* __restrict__ counts)
{
    int i = blockIdx.x*256 + threadIdx.x;              // 0 .. 639999
    if (i < NNODES*HDIM){ h[i] = 0.f; G[i] = cvec[i&63]; }
    if (i < NNODES*LDIM) lice[i] = init_lice[i];
    if (i < NNODES) counts[i] = 0;
    if (i < 2048)       packB(en_w1,   5,  0,  5, 1, F_en1h, F_en1l, i);
    else if (i < 6144)  packB(en_w2,  64,  0, 64, 2, F_enh,  F_enl,  i-2048);
    else if (i < 24576) packB(gru_wih,72,  0, 72, 3, F_ihh,  F_ihl,  i-6144);
    else if (i < 36864) packB(gru_whh,64,  0, 64, 2, F_hhh,  F_hhl,  i-24576);
    else if (i < 40960) packB(de_w1,  64,  0, 64, 2, F_deh,  F_del,  i-36864);
    else if (i < 45056) packB(at_w1, 128, 64, 64, 2, F_a2h,  F_a2l,  i-40960);
}

// fec depends only on temp -> precompute for all (t,n)
__global__ void __launch_bounds__(256) k_fec(
    const float* __restrict__ nfs,
    const float* __restrict__ fe_w1, const float* __restrict__ fe_b1,
    const float* __restrict__ fe_w2, const float* __restrict__ fe_b2,
    const float* __restrict__ fe_w3, const float* __restrict__ fe_b3,
    float* __restrict__ fec_arr)
{
    int i = blockIdx.x*256 + threadIdx.x;
    if (i >= T_STEPS*NNODES) return;
    float temp = nfs[(size_t)i*NFEAT + 11];
    float tn = (temp - 10.f)*(1.f/5.f);
    float a[32];
    #pragma unroll
    for (int k=0;k<32;++k) a[k] = fmaxf(tn*fe_w1[k] + fe_b1[k], 0.f);
    float o = fe_b3[0];
    #pragma unroll 4
    for (int l=0;l<32;++l){
        float b = fe_b2[l];
        #pragma unroll
        for (int k=0;k<32;++k) b += a[k]*fe_w2[l*32+k];
        o += fmaxf(b, 0.f)*fe_w3[l];
    }
    fec_arr[i] = softplusf_(o);
}

__global__ void __launch_bounds__(256) k_hist(const int* __restrict__ ei_dst, int* __restrict__ counts){
    int e = blockIdx.x*256 + threadIdx.x;
    if (e < NEDGES) atomicAdd(&counts[ei_dst[e]], 1);
}

__global__ void __launch_bounds__(1024) k_scan(const int* __restrict__ counts,
                                               int* __restrict__ rowptr, int* __restrict__ cursor){
    __shared__ int sums[1024];
    int t = threadIdx.x;
    const int CH = 10;
    int c0 = t*CH;
    int s = 0;
    if (c0 < NNODES){
        #pragma unroll
        for (int i=0;i<CH;i++) s += counts[c0+i];
    }
    sums[t] = s;
    __syncthreads();
    for (int off=1; off<1024; off<<=1){
        int v = (t>=off) ? sums[t-off] : 0;
        __syncthreads();
        sums[t] += v;
        __syncthreads();
    }
    if (c0 < NNODES){
        int run = (t==0) ? 0 : sums[t-1];
        for (int i=0;i<CH;i++){ rowptr[c0+i] = run; run += counts[c0+i]; cursor[c0+i] = 0; }
        if (t == (NNODES/CH)-1) rowptr[NNODES] = run;
    }
}

__global__ void __launch_bounds__(256) k_scatter(const int* __restrict__ ei_dst,
        const int* __restrict__ rowptr, int* __restrict__ cursor, int* __restrict__ perm){
    int e = blockIdx.x*256 + threadIdx.x;
    if (e >= NEDGES) return;
    int d = ei_dst[e];
    int pos = rowptr[d] + atomicAdd(&cursor[d], 1);
    perm[pos] = e;
}

// pre-gather step-invariant per-edge data into CSR (perm) order
__global__ void __launch_bounds__(256) k_permg(
    const int* __restrict__ perm, const int* __restrict__ ei_src,
    const float* __restrict__ dist, const float* __restrict__ dirn,
    int* __restrict__ src_perm, float* __restrict__ dist_p, float* __restrict__ dirn_p)
{
    int i = blockIdx.x*256 + threadIdx.x;
    if (i >= NEDGES) return;
    int e = perm[i];
    src_perm[i] = ei_src[e];
    dist_p[i] = dist[e];
    float2 dd = *reinterpret_cast<const float2*>(dirn + 2*e);
    *reinterpret_cast<float2*>(dirn_p + 2*i) = dd;
}

// ---------------- per-step kernel 1: edge MLPs -> logits (MFMA fp16x3) ----------------

__global__ void __launch_bounds__(256,2) k_edge_mfma(
    const float* __restrict__ xt, const float* __restrict__ G,
    const int* __restrict__ src_perm,
    const float* __restrict__ dist_p, const float* __restrict__ dirn_p,
    const float* __restrict__ ee_w1, const float* __restrict__ ee_b1,
    const _Float16* __restrict__ P_Mhi, const _Float16* __restrict__ P_Mlo,
    const float* __restrict__ at_w2, const float* __restrict__ at_b2,
    float* __restrict__ logits)
{
    __shared__ __align__(16) _Float16 smh[36864];   // A_hi [256][72] | A_lo [256][72]; reused for C
    float* smf = (float*)smh;

    const int tid = threadIdx.x;
    const int wv = tid>>6, lane = tid&63;
    const int e = blockIdx.x*256 + tid;

    f16x8 bh[4][2], bl[4][2];
    #pragma unroll
    for (int jt=0;jt<4;++jt){
        #pragma unroll
        for (int ks=0;ks<2;++ks){
            bh[jt][ks] = *(const f16x8*)(P_Mhi + (((jt*2+ks)*64 + lane)*8));
            bl[jt][ks] = *(const f16x8*)(P_Mlo + (((jt*2+ks)*64 + lane)*8));
        }
    }

    const int src = src_perm[e];
    const float d  = dist_p[e];
    float2 dir2 = *reinterpret_cast<const float2*>(dirn_p + 2*e);
    float temp = xt[src*NFEAT+11];
    float4 q  = *reinterpret_cast<const float4*>(xt + src*NFEAT + 12);
    float flux = q.y*dir2.x + q.z*dir2.y;
    float wflux = fmaxf(flux, 0.f) * __expf(-d*(1.f/15.f));
    const float a0 = d, a1 = wflux, a2 = temp, a3 = q.x;
    const float lbias = at_b2[0] + __logf(wflux + 1e-8f);

    #pragma unroll
    for (int kb=0;kb<8;++kb){
        f16x8 hv, lv;
        #pragma unroll
        for (int i=0;i<8;++i){
            const int m = kb*8+i;
            float4 w1 = *reinterpret_cast<const float4*>(ee_w1 + m*4);
            float r = fmaxf(ee_b1[m] + a0*w1.x + a1*w1.y + a2*w1.z + a3*w1.w, 0.f);
            _Float16 hi = (_Float16)r;
            hv[i] = hi;
            lv[i] = (_Float16)(r - (float)hi);
        }
        *(f16x8*)(smh + tid*72 + kb*8)         = hv;
        *(f16x8*)(smh + 18432 + tid*72 + kb*8) = lv;
    }
    asm volatile("s_waitcnt lgkmcnt(0)" ::: "memory");

    f32x4 c[4][4];
    #pragma unroll
    for (int et=0;et<4;++et)
        #pragma unroll
        for (int jt=0;jt<4;++jt)
            c[et][jt] = (f32x4){0.f,0.f,0.f,0.f};

    #pragma unroll
    for (int et=0;et<4;++et){
        #pragma unroll
        for (int ks=0;ks<2;++ks){
            const int row = wv*64 + et*16 + (lane&15);
            f16x8 ah = *(const f16x8*)(smh + row*72 + ks*32 + (lane>>4)*8);
            f16x8 al = *(const f16x8*)(smh + 18432 + row*72 + ks*32 + (lane>>4)*8);
            #pragma unroll
            for (int jt=0;jt<4;++jt){
                c[et][jt] = __builtin_amdgcn_mfma_f32_16x16x32_f16(ah, bh[jt][ks], c[et][jt], 0,0,0);
                c[et][jt] = __builtin_amdgcn_mfma_f32_16x16x32_f16(ah, bl[jt][ks], c[et][jt], 0,0,0);
                c[et][jt] = __builtin_amdgcn_mfma_f32_16x16x32_f16(al, bh[jt][ks], c[et][jt], 0,0,0);
            }
        }
    }
    asm volatile("s_waitcnt lgkmcnt(0)" ::: "memory");

    #pragma unroll
    for (int et=0;et<4;++et){
        #pragma unroll
        for (int jt=0;jt<4;++jt){
            #pragma unroll
            for (int i=0;i<4;++i){
                const int rl = et*16 + ((lane>>4)&3)*4 + i;
                const int col = jt*16 + (lane&15);
                const int idx = (et < 2) ? (wv*2304 + rl*68 + col)
                                         : (9216 + wv*2304 + (rl-32)*68 + col);
                smf[idx] = c[et][jt][i];
            }
        }
    }
    asm volatile("s_waitcnt lgkmcnt(0)" ::: "memory");

    const int el = tid & 63;
    const float* crow = smf + ((el < 32) ? (wv*2304 + el*68)
                                         : (9216 + wv*2304 + (el-32)*68));
    const float4* G4 = reinterpret_cast<const float4*>(G + src*HDIM);
    float logit = lbias;
    #pragma unroll
    for (int jj=0;jj<16;++jj){
        float4 cv = *reinterpret_cast<const float4*>(crow + jj*4);
        float4 gv = G4[jj];
        float4 w4 = *reinterpret_cast<const float4*>(at_w2 + jj*4);
        logit += w4.x*fmaxf(cv.x+gv.x,0.f) + w4.y*fmaxf(cv.y+gv.y,0.f)
               + w4.z*fmaxf(cv.z+gv.z,0.f) + w4.w*fmaxf(cv.w+gv.w,0.f);
    }
    logits[e] = logit;
}

// ---------------- per-step kernel 2: segment softmax + pressure ----------------

__global__ void __launch_bounds__(256) k_softmax_pressure(
    const float* __restrict__ logits, const float* __restrict__ h,
    const float* __restrict__ lice, const int* __restrict__ src_perm,
    const int* __restrict__ rowptr,
    const float* __restrict__ log_beta,
    float* __restrict__ pressure)
{
    __shared__ float swgt[CAP];
    __shared__ int   ssrc[CAP];
    __shared__ float sred[4][64];
    __shared__ float sredm[4], sreds[4];

    const int node = blockIdx.x;
    const int tid = threadIdx.x;
    const int wid = tid >> 6;
    const int lane = tid & 63;
    const int start = rowptr[node], end = rowptr[node+1];
    const int deg = end - start;
    const int nfast = deg < CAP ? deg : CAP;

    float m = -INFINITY;
    for (int i=start+tid; i<end; i+=256){
        float lg = logits[i];
        int o = i - start;
        if (o < CAP){ swgt[o] = lg; ssrc[o] = src_perm[i]; }
        m = fmaxf(m, lg);
    }
    #pragma unroll
    for (int off=32; off>=1; off>>=1) m = fmaxf(m, __shfl_xor(m, off));
    if (lane == 0) sredm[wid] = m;
    __syncthreads();
    m = fmaxf(fmaxf(sredm[0], sredm[1]), fmaxf(sredm[2], sredm[3]));

    float s = 0.f;
    for (int i=start+tid; i<end; i+=256){
        int o = i - start;
        float lg = (o < CAP) ? swgt[o] : logits[i];
        s += __expf(lg - m);
    }
    #pragma unroll
    for (int off=32; off>=1; off>>=1) s += __shfl_xor(s, off);
    if (lane == 0) sreds[wid] = s;
    __syncthreads();
    s = (sreds[0]+sreds[1])+(sreds[2]+sreds[3]);

    const float binv = __expf(log_beta[0])/(s + 1e-8f);

    for (int o=tid; o<nfast; o+=256){
        int sc = ssrc[o];
        swgt[o] = __expf(swgt[o] - m) * binv * lice[sc*LDIM];
    }
    __syncthreads();

    float p = 0.f;
    for (int o=wid; o<nfast; o+=4)
        p += swgt[o]*h[ssrc[o]*HDIM + lane];
    for (int i=start+CAP+wid; i<end; i+=4){
        int sc = src_perm[i];
        float wg = __expf(logits[i]-m)*binv*lice[sc*LDIM];
        p += wg*h[sc*HDIM+lane];
    }
    sred[wid][lane] = p;
    __syncthreads();
    if (wid == 0)
        pressure[node*HDIM + lane] = (sred[0][lane]+sred[1][lane])+(sred[2][lane]+sred[3][lane]);
}

// ---------------- per-step kernel 3: node update via MFMA (fp16 hi/lo x3) ----------------
// Block = 64 nodes, 256 threads = 4 waves. All GEMMs on matrix cores.
// Wave w owns output col-tiles: enc/dec/G: jt=w; gates: jt in {w, w+4, w+8} so that
// r/z/n for hidden col j=w*16+(lane&15) land in the SAME lane -> in-register GRU glue.

__global__ void __launch_bounds__(256,1) k_node_mfma(
    const float* __restrict__ xt,
    float* __restrict__ h, float* __restrict__ lice,
    const float* __restrict__ pressure,
    const _Float16* __restrict__ F_en1h, const _Float16* __restrict__ F_en1l,
    const _Float16* __restrict__ F_enh,  const _Float16* __restrict__ F_enl,
    const _Float16* __restrict__ F_ihh,  const _Float16* __restrict__ F_ihl,
    const _Float16* __restrict__ F_hhh,  const _Float16* __restrict__ F_hhl,
    const _Float16* __restrict__ F_deh,  const _Float16* __restrict__ F_del,
    const _Float16* __restrict__ F_a2h,  const _Float16* __restrict__ F_a2l,
    const float* __restrict__ en_b1, const float* __restrict__ en_b2,
    const float* __restrict__ gru_bih, const float* __restrict__ gru_bhh,
    const float* __restrict__ de_b1, const float* __restrict__ de_w2, const float* __restrict__ de_b2,
    const float* __restrict__ cvec, const float* __restrict__ fec_t,
    const float* __restrict__ temp_sens,
    float* __restrict__ G, float* __restrict__ out_t)
{
    __shared__ __align__(16) _Float16 Ah_hi[64*72], Ah_lo[64*72];    // h tile, then hnew tile
    __shared__ __align__(16) _Float16 At_hi[64*72], At_lo[64*72];    // t1 (enc1 out)
    __shared__ __align__(16) _Float16 Ad_hi[64*104], Ad_lo[64*104];  // din tile (K=96 used)
    __shared__ float s_pd[64*64];                                    // pressure, then d1
    __shared__ float s_fec[64];

    const int tid = threadIdx.x;
    const int w = tid>>6, lane = tid&63;
    const int l15 = lane & 15, lq = (lane>>4)&3;
    const int n0 = blockIdx.x*64;
    const int nvalid = (NNODES - n0 < 64) ? (NNODES - n0) : 64;

    // ---- phase 1: stage h (hi/lo), pressure, env/lice cols, fec ----
    #pragma unroll
    for (int it=0; it<4; ++it){
        int idx = tid + it*256;            // 0..1023 float4 slots
        int node = idx>>4, k4 = idx&15;
        int nc = n0 + (node < nvalid ? node : nvalid-1);
        float4 hv = *reinterpret_cast<const float4*>(h + nc*64 + k4*4);
        float4 pv = *reinterpret_cast<const float4*>(pressure + nc*64 + k4*4);
        *reinterpret_cast<float4*>(s_pd + node*64 + k4*4) = pv;
        f16x4 hh, hl;
        hh[0]=(_Float16)hv.x; hh[1]=(_Float16)hv.y; hh[2]=(_Float16)hv.z; hh[3]=(_Float16)hv.w;
        hl[0]=(_Float16)(hv.x-(float)hh[0]); hl[1]=(_Float16)(hv.y-(float)hh[1]);
        hl[2]=(_Float16)(hv.z-(float)hh[2]); hl[3]=(_Float16)(hv.w-(float)hh[3]);
        *reinterpret_cast<f16x4*>(Ah_hi + node*72 + k4*4) = hh;
        *reinterpret_cast<f16x4*>(Ah_lo + node*72 + k4*4) = hl;
    }
    if (w == 0){
        int nc = n0 + (lane < nvalid ? lane : nvalid-1);
        float ev[8];
        ev[0]=xt[nc*16+11]; ev[1]=xt[nc*16+12]; ev[2]=xt[nc*16+13];
        ev[3]=xt[nc*16+14]; ev[4]=xt[nc*16+15];
        ev[5]=lice[nc*3+0]; ev[6]=lice[nc*3+1]; ev[7]=lice[nc*3+2];
        s_fec[lane] = fec_t[nc];
        f16x8 eh, el;
        #pragma unroll
        for (int i=0;i<8;++i){ eh[i]=(_Float16)ev[i]; el[i]=(_Float16)(ev[i]-(float)eh[i]); }
        *reinterpret_cast<f16x8*>(Ad_hi + lane*104 + 64) = eh;
        *reinterpret_cast<f16x8*>(Ad_lo + lane*104 + 64) = el;
        f16x8 zz = {(_Float16)0,(_Float16)0,(_Float16)0,(_Float16)0,
                    (_Float16)0,(_Float16)0,(_Float16)0,(_Float16)0};
        *reinterpret_cast<f16x8*>(Ad_hi + lane*104 + 72) = zz;
        *reinterpret_cast<f16x8*>(Ad_hi + lane*104 + 80) = zz;
        *reinterpret_cast<f16x8*>(Ad_hi + lane*104 + 88) = zz;
        *reinterpret_cast<f16x8*>(Ad_lo + lane*104 + 72) = zz;
        *reinterpret_cast<f16x8*>(Ad_lo + lane*104 + 80) = zz;
        *reinterpret_cast<f16x8*>(Ad_lo + lane*104 + 88) = zz;
    }
    __syncthreads();

    // ---- phase 2a: enc1 (K=5 padded to 32; A = env/lice slice of Ad at k-offset 64) ----
    {
        f16x8 bh = *(const f16x8*)(F_en1h + (w*64+lane)*8);
        f16x8 bl = *(const f16x8*)(F_en1l + (w*64+lane)*8);
        f32x4 c[4];
        #pragma unroll
        for (int et=0;et<4;++et) c[et] = (f32x4){0.f,0.f,0.f,0.f};
        #pragma unroll
        for (int et=0;et<4;++et){
            int row = et*16 + l15;
            f16x8 ah = *(const f16x8*)(Ad_hi + row*104 + 64 + lq*8);
            f16x8 al = *(const f16x8*)(Ad_lo + row*104 + 64 + lq*8);
            c[et] = __builtin_amdgcn_mfma_f32_16x16x32_f16(ah, bh, c[et],0,0,0);
            c[et] = __builtin_amdgcn_mfma_f32_16x16x32_f16(ah, bl, c[et],0,0,0);
            c[et] = __builtin_amdgcn_mfma_f32_16x16x32_f16(al, bh, c[et],0,0,0);
        }
        int col = w*16 + l15;
        float b1 = en_b1[col];
        #pragma unroll
        for (int et=0;et<4;++et){
            #pragma unroll
            for (int i=0;i<4;++i){
                int row = et*16 + lq*4 + i;
                float v = fmaxf(c[et][i] + b1, 0.f);
                _Float16 hi = (_Float16)v;
                At_hi[row*72+col] = hi;
                At_lo[row*72+col] = (_Float16)(v-(float)hi);
            }
        }
    }
    __syncthreads();

    // ---- phase 2b: enc2 + pressure -> din cols 0..63 ----
    {
        f32x4 c[4];
        #pragma unroll
        for (int et=0;et<4;++et) c[et] = (f32x4){0.f,0.f,0.f,0.f};
        #pragma unroll
        for (int ks=0; ks<2; ++ks){
            f16x8 bh = *(const f16x8*)(F_enh + ((w*2+ks)*64+lane)*8);
            f16x8 bl = *(const f16x8*)(F_enl + ((w*2+ks)*64+lane)*8);
            #pragma unroll
            for (int et=0;et<4;++et){
                int row = et*16 + l15;
                f16x8 ah = *(const f16x8*)(At_hi + row*72 + ks*32 + lq*8);
                f16x8 al = *(const f16x8*)(At_lo + row*72 + ks*32 + lq*8);
                c[et] = __builtin_amdgcn_mfma_f32_16x16x32_f16(ah, bh, c[et],0,0,0);
                c[et] = __builtin_amdgcn_mfma_f32_16x16x32_f16(ah, bl, c[et],0,0,0);
                c[et] = __builtin_amdgcn_mfma_f32_16x16x32_f16(al, bh, c[et],0,0,0);
            }
        }
        int col = w*16 + l15;
        float b2 = en_b2[col];
        #pragma unroll
        for (int et=0;et<4;++et){
            #pragma unroll
            for (int i=0;i<4;++i){
                int row = et*16 + lq*4 + i;
                float v = c[et][i] + b2 + s_pd[row*64+col];
                _Float16 hi = (_Float16)v;
                Ad_hi[row*104+col] = hi;
                Ad_lo[row*104+col] = (_Float16)(v-(float)hi);
            }
        }
    }
    __syncthreads();

    // ---- phase 3: GRU gates. gates = din@Wih^T + h@Whh^T (+biases). ----
    f32x4 Cr[4], Cz[4], Ci[4], Chn[4];
    {
        int col = w*16 + l15;
        float br = gru_bih[col]     + gru_bhh[col];
        float bz = gru_bih[64+col]  + gru_bhh[64+col];
        float bi = gru_bih[128+col];
        float bn = gru_bhh[128+col];
        #pragma unroll
        for (int et=0;et<4;++et){
            Cr[et]  = (f32x4){br,br,br,br};
            Cz[et]  = (f32x4){bz,bz,bz,bz};
            Ci[et]  = (f32x4){bi,bi,bi,bi};
            Chn[et] = (f32x4){bn,bn,bn,bn};
        }
    }
    // din side: K=96 (3 ks); jt = w (r), 4+w (z), 8+w (n -> Ci)
    #pragma unroll
    for (int ks=0; ks<3; ++ks){
        f16x8 ah[4], al[4];
        #pragma unroll
        for (int et=0;et<4;++et){
            int row = et*16 + l15;
            ah[et] = *(const f16x8*)(Ad_hi + row*104 + ks*32 + lq*8);
            al[et] = *(const f16x8*)(Ad_lo + row*104 + ks*32 + lq*8);
        }
        {
            int fi = w*3 + ks;
            f16x8 bh = *(const f16x8*)(F_ihh + (fi*64+lane)*8);
            f16x8 bl = *(const f16x8*)(F_ihl + (fi*64+lane)*8);
            #pragma unroll
            for (int et=0;et<4;++et){
                Cr[et] = __builtin_amdgcn_mfma_f32_16x16x32_f16(ah[et], bh, Cr[et],0,0,0);
                Cr[et] = __builtin_amdgcn_mfma_f32_16x16x32_f16(ah[et], bl, Cr[et],0,0,0);
                Cr[et] = __builtin_amdgcn_mfma_f32_16x16x32_f16(al[et], bh, Cr[et],0,0,0);
            }
        }
        {
            int fi = (4+w)*3 + ks;
            f16x8 bh = *(const f16x8*)(F_ihh + (fi*64+lane)*8);
            f16x8 bl = *(const f16x8*)(F_ihl + (fi*64+lane)*8);
            #pragma unroll
            for (int et=0;et<4;++et){
                Cz[et] = __builtin_amdgcn_mfma_f32_16x16x32_f16(ah[et], bh, Cz[et],0,0,0);
                Cz[et] = __builtin_amdgcn_mfma_f32_16x16x32_f16(ah[et], bl, Cz[et],0,0,0);
                Cz[et] = __builtin_amdgcn_mfma_f32_16x16x32_f16(al[et], bh, Cz[et],0,0,0);
            }
        }
        {
            int fi = (8+w)*3 + ks;
            f16x8 bh = *(const f16x8*)(F_ihh + (fi*64+lane)*8);
            f16x8 bl = *(const f16x8*)(F_ihl + (fi*64+lane)*8);
            #pragma unroll
            for (int et=0;et<4;++et){
                Ci[et] = __builtin_amdgcn_mfma_f32_16x16x32_f16(ah[et], bh, Ci[et],0,0,0);
                Ci[et] = __builtin_amdgcn_mfma_f32_16x16x32_f16(ah[et], bl, Ci[et],0,0,0);
                Ci[et] = __builtin_amdgcn_mfma_f32_16x16x32_f16(al[et], bh, Ci[et],0,0,0);
            }
        }
    }
    // h side: K=64 (2 ks); jt = w (r), 4+w (z), 8+w (n -> Chn)
    #pragma unroll
    for (int ks=0; ks<2; ++ks){
        f16x8 ah[4], al[4];
        #pragma unroll
        for (int et=0;et<4;++et){
            int row = et*16 + l15;
            ah[et] = *(const f16x8*)(Ah_hi + row*72 + ks*32 + lq*8);
            al[et] = *(const f16x8*)(Ah_lo + row*72 + ks*32 + lq*8);
        }
        {
            int fi = w*2 + ks;
            f16x8 bh = *(const f16x8*)(F_hhh + (fi*64+lane)*8);
            f16x8 bl = *(const f16x8*)(F_hhl + (fi*64+lane)*8);
            #pragma unroll
            for (int et=0;et<4;++et){
                Cr[et] = __builtin_amdgcn_mfma_f32_16x16x32_f16(ah[et], bh, Cr[et],0,0,0);
                Cr[et] = __builtin_amdgcn_mfma_f32_16x16x32_f16(ah[et], bl, Cr[et],0,0,0);
                Cr[et] = __builtin_amdgcn_mfma_f32_16x16x32_f16(al[et], bh, Cr[et],0,0,0);
            }
        }
        {
            int fi = (4+w)*2 + ks;
            f16x8 bh = *(const f16x8*)(F_hhh + (fi*64+lane)*8);
            f16x8 bl = *(const f16x8*)(F_hhl + (fi*64+lane)*8);
            #pragma unroll
            for (int et=0;et<4;++et){
                Cz[et] = __builtin_amdgcn_mfma_f32_16x16x32_f16(ah[et], bh, Cz[et],0,0,0);
                Cz[et] = __builtin_amdgcn_mfma_f32_16x16x32_f16(ah[et], bl, Cz[et],0,0,0);
                Cz[et] = __builtin_amdgcn_mfma_f32_16x16x32_f16(al[et], bh, Cz[et],0,0,0);
            }
        }
        {
            int fi = (8+w)*2 + ks;
            f16x8 bh = *(const f16x8*)(F_hhh + (fi*64+lane)*8);
            f16x8 bl = *(const f16x8*)(F_hhl + (fi*64+lane)*8);
            #pragma unroll
            for (int et=0;et<4;++et){
                Chn[et] = __builtin_amdgcn_mfma_f32_16x16x32_f16(ah[et], bh, Chn[et],0,0,0);
                Chn[et] = __builtin_amdgcn_mfma_f32_16x16x32_f16(ah[et], bl, Chn[et],0,0,0);
                Chn[et] = __builtin_amdgcn_mfma_f32_16x16x32_f16(al[et], bh, Chn[et],0,0,0);
            }
        }
    }

    // ---- GRU glue fully in registers (hold = hi+lo reconstruction from Ah tile) ----
    float hnv[16];
    {
        const int coln = w*16 + l15;
        #pragma unroll
        for (int et=0;et<4;++et){
            #pragma unroll
            for (int i=0;i<4;++i){
                int row = et*16 + lq*4 + i;
                float r  = sigmoidf_(Cr[et][i]);
                float z  = sigmoidf_(Cz[et][i]);
                float nn = tanhf_(Ci[et][i] + r*Chn[et][i]);
                float hold = (float)Ah_hi[row*72+coln] + (float)Ah_lo[row*72+coln];
                hnv[et*4+i] = (1.f-z)*nn + z*hold;
            }
        }
    }
    __syncthreads();                 // all waves done reading Ah/Ad tiles
    {
        const int coln = w*16 + l15;
        #pragma unroll
        for (int et=0;et<4;++et){
            #pragma unroll
            for (int i=0;i<4;++i){
                int row = et*16 + lq*4 + i;
                float v = hnv[et*4+i];
                if (row < nvalid) h[(n0+row)*HDIM + coln] = v;
                _Float16 hi = (_Float16)v;
                Ah_hi[row*72+coln] = hi;
                Ah_lo[row*72+coln] = (_Float16)(v-(float)hi);
            }
        }
    }
    __syncthreads();

    // ---- phase C: dec1 (relu -> s_pd) and G = cvec + hnew@A2 ----
    {
        int col = w*16 + l15;
        float bd = de_b1[col], bg = cvec[col];
        f32x4 Cd[4], Cg[4];
        #pragma unroll
        for (int et=0;et<4;++et){ Cd[et]=(f32x4){bd,bd,bd,bd}; Cg[et]=(f32x4){bg,bg,bg,bg}; }
        #pragma unroll
        for (int ks=0;ks<2;++ks){
            f16x8 ah[4], al[4];
            #pragma unroll
            for (int et=0;et<4;++et){
                int row = et*16 + l15;
                ah[et] = *(const f16x8*)(Ah_hi + row*72 + ks*32 + lq*8);
                al[et] = *(const f16x8*)(Ah_lo + row*72 + ks*32 + lq*8);
            }
            f16x8 dh = *(const f16x8*)(F_deh + ((w*2+ks)*64+lane)*8);
            f16x8 dl = *(const f16x8*)(F_del + ((w*2+ks)*64+lane)*8);
            f16x8 gh = *(const f16x8*)(F_a2h + ((w*2+ks)*64+lane)*8);
            f16x8 gl = *(const f16x8*)(F_a2l + ((w*2+ks)*64+lane)*8);
            #pragma unroll
            for (int et=0;et<4;++et){
                Cd[et] = __builtin_amdgcn_mfma_f32_16x16x32_f16(ah[et], dh, Cd[et],0,0,0);
                Cd[et] = __builtin_amdgcn_mfma_f32_16x16x32_f16(ah[et], dl, Cd[et],0,0,0);
                Cd[et] = __builtin_amdgcn_mfma_f32_16x16x32_f16(al[et], dh, Cd[et],0,0,0);
                Cg[et] = __builtin_amdgcn_mfma_f32_16x16x32_f16(ah[et], gh, Cg[et],0,0,0);
                Cg[et] = __builtin_amdgcn_mfma_f32_16x16x32_f16(ah[et], gl, Cg[et],0,0,0);
                Cg[et] = __builtin_amdgcn_mfma_f32_16x16x32_f16(al[et], gh, Cg[et],0,0,0);
            }
        }
        #pragma unroll
        for (int et=0;et<4;++et){
            #pragma unroll
            for (int i=0;i<4;++i){
                int row = et*16 + lq*4 + i;
                if (row < nvalid) G[(n0+row)*HDIM + col] = Cg[et][i];
                s_pd[row*64+col] = fmaxf(Cd[et][i], 0.f);
            }
        }
    }
    __syncthreads();

    // ---- dec2: out = softplus(de_w2 @ d1 + b) * (1 + ts*(fec-1)) ----
    {
        float ts = temp_sens[0];
        #pragma unroll 1
        for (int m=0;m<16;++m){
            int node = w*16 + m;
            float d1v = s_pd[node*64 + lane];
            float s0 = d1v*de_w2[lane];
            float s1 = d1v*de_w2[64+lane];
            float s2 = d1v*de_w2[128+lane];
            #pragma unroll
            for (int off=32; off>=1; off>>=1){
                s0 += __shfl_xor(s0,off);
                s1 += __shfl_xor(s1,off);
                s2 += __shfl_xor(s2,off);
            }
            if (lane < LDIM && node < nvalid){
                float fec = s_fec[node];
                float oi = (lane==0?s0:(lane==1?s1:s2)) + de_b2[lane];
                float lb = softplusf_(oi);
                float ln = lb*(1.f + ts*(fec-1.f));
                lice[(n0+node)*LDIM+lane] = ln;
                out_t[(n0+node)*LDIM+lane] = ln;
            }
        }
    }
}

// ---------------- launcher ----------------

extern "C" void kernel_launch(void* const* d_in, const int* in_sizes, int n_in,
                              void* d_out, int out_size, void* d_ws, size_t ws_size,
                              hipStream_t stream) {
    const float* nfs       = (const float*)d_in[0];
    const float* init_lice = (const float*)d_in[1];
    const float* dist      = (const float*)d_in[2];
    const float* dirn      = (const float*)d_in[3];
    const float* ee_w1     = (const float*)d_in[4];
    const float* ee_b1     = (const float*)d_in[5];
    const float* ee_w2     = (const float*)d_in[6];
    const float* ee_b2     = (const float*)d_in[7];
    const float* at_w1     = (const float*)d_in[8];
    const float* at_b1     = (const float*)d_in[9];
    const float* at_w2     = (const float*)d_in[10];
    const float* at_b2     = (const float*)d_in[11];
    const float* en_w1     = (const float*)d_in[12];
    const float* en_b1     = (const float*)d_in[13];
    const float* en_w2     = (const float*)d_in[14];
    const float* en_b2     = (const float*)d_in[15];
    const float* fe_w1     = (const float*)d_in[16];
    const float* fe_b1     = (const float*)d_in[17];
    const float* fe_w2     = (const float*)d_in[18];
    const float* fe_b2     = (const float*)d_in[19];
    const float* fe_w3     = (const float*)d_in[20];
    const float* fe_b3     = (const float*)d_in[21];
    const float* gru_wih   = (const float*)d_in[22];
    const float* gru_whh   = (const float*)d_in[23];
    const float* gru_bih   = (const float*)d_in[24];
    const float* gru_bhh   = (const float*)d_in[25];
    const float* de_w1     = (const float*)d_in[26];
    const float* de_b1     = (const float*)d_in[27];
    const float* de_w2     = (const float*)d_in[28];
    const float* de_b2     = (const float*)d_in[29];
    const float* log_beta  = (const float*)d_in[30];
    const float* temp_sens = (const float*)d_in[31];
    const int*   ei        = (const int*)d_in[32];
    const int*   ei_src = ei;
    const int*   ei_dst = ei + NEDGES;
    float* out = (float*)d_out;

    // workspace carve (floats; keep offsets %4 for 16B alignment)
    float* wsf = (float*)d_ws;
    size_t off = 0;
    float* h        = wsf + off; off += (size_t)NNODES*HDIM;
    float* lice     = wsf + off; off += (size_t)NNODES*LDIM + 2;
    off = (off + 3) & ~(size_t)3;
    float* logits   = wsf + off; off += (size_t)NEDGES;
    float* pressure = wsf + off; off += (size_t)NNODES*HDIM;
    float* G        = wsf + off; off += (size_t)NNODES*HDIM;
    float* cvec     = wsf + off; off += 64;
    _Float16* P_Mhi = (_Float16*)(wsf + off); off += 2048;     // 4096 halves
    _Float16* P_Mlo = (_Float16*)(wsf + off); off += 2048;
    _Float16* F_en1h= (_Float16*)(wsf + off); off += 1024;     // 2048 halves
    _Float16* F_en1l= (_Float16*)(wsf + off); off += 1024;
    _Float16* F_enh = (_Float16*)(wsf + off); off += 2048;     // 4096 halves
    _Float16* F_enl = (_Float16*)(wsf + off); off += 2048;
    _Float16* F_ihh = (_Float16*)(wsf + off); off += 9216;     // 18432 halves
    _Float16* F_ihl = (_Float16*)(wsf + off); off += 9216;
    _Float16* F_hhh = (_Float16*)(wsf + off); off += 6144;     // 12288 halves
    _Float16* F_hhl = (_Float16*)(wsf + off); off += 6144;
    _Float16* F_deh = (_Float16*)(wsf + off); off += 2048;
    _Float16* F_del = (_Float16*)(wsf + off); off += 2048;
    _Float16* F_a2h = (_Float16*)(wsf + off); off += 2048;
    _Float16* F_a2l = (_Float16*)(wsf + off); off += 2048;
    float* fec_arr  = wsf + off; off += (size_t)T_STEPS*NNODES;
    float* dist_p   = wsf + off; off += NEDGES;
    float* dirn_p   = wsf + off; off += 2*NEDGES;
    int* src_perm = (int*)(wsf + off); off += NEDGES;
    int* counts = (int*)(wsf + off); off += NNODES;
    int* rowptr = (int*)(wsf + off); off += NNODES+1;
    int* cursor = (int*)(wsf + off); off += NNODES;
    int* perm   = (int*)(wsf + off); off += NEDGES;

    // setup (k_prep first: k_init consumes cvec)
    k_prep<<<16,256,0,stream>>>(ee_w2, ee_b2, at_w1, at_b1, P_Mhi, P_Mlo, cvec);
    k_init<<<2500,256,0,stream>>>(init_lice, cvec,
                                  en_w1, en_w2, gru_wih, gru_whh, de_w1, at_w1,
                                  h, lice, G,
                                  F_en1h, F_en1l, F_enh, F_enl,
                                  F_ihh, F_ihl, F_hhh, F_hhl,
                                  F_deh, F_del, F_a2h, F_a2l,
                                  counts);
    k_fec<<<(T_STEPS*NNODES+255)/256,256,0,stream>>>(nfs, fe_w1, fe_b1, fe_w2, fe_b2,
                                                     fe_w3, fe_b3, fec_arr);
    k_hist<<<1250,256,0,stream>>>(ei_dst, counts);
    k_scan<<<1,1024,0,stream>>>(counts, rowptr, cursor);
    k_scatter<<<1250,256,0,stream>>>(ei_dst, rowptr, cursor, perm);
    k_permg<<<1250,256,0,stream>>>(perm, ei_src, dist, dirn, src_perm, dist_p, dirn_p);

    const int node_blocks = (NNODES + 63)/64;   // 157
    for (int t=0; t<T_STEPS; ++t){
        const float* xt = nfs + (size_t)t*NNODES*NFEAT;
        k_edge_mfma<<<1250,256,0,stream>>>(xt, G, src_perm, dist_p, dirn_p,
                                           ee_w1, ee_b1, P_Mhi, P_Mlo,
                                           at_w2, at_b2, logits);
        k_softmax_pressure<<<NNODES,256,0,stream>>>(logits, h, lice, src_perm,
                                                    rowptr, log_beta, pressure);
        k_node_mfma<<<node_blocks,256,0,stream>>>(xt, h, lice, pressure,
                                           F_en1h, F_en1l, F_enh, F_enl,
                                           F_ihh, F_ihl, F_hhh, F_hhl,
                                           F_deh, F_del, F_a2h, F_a2l,
                                           en_b1, en_b2, gru_bih, gru_bhh,
                                           de_b1, de_w2, de_b2,
                                           cvec, fec_arr + (size_t)t*NNODES,
                                           temp_sens,
                                           G, out + (size_t)t*NNODES*LDIM);
    }
}

// Round 10
// 756.602 us; speedup vs baseline: 1.4610x; 1.1036x over previous
//
#include <hip/hip_runtime.h>
#include <math.h>

#define T_STEPS 8
#define NNODES 10000
#define NFEAT 16
#define NEDGES 320000
#define HDIM 64
#define LDIM 3
#define CAP 128

typedef _Float16 f16x8 __attribute__((ext_vector_type(8)));
typedef _Float16 f16x4 __attribute__((ext_vector_type(4)));
typedef float f32x4 __attribute__((ext_vector_type(4)));

__device__ __forceinline__ float sigmoidf_(float x){ return 1.f/(1.f+__expf(-x)); }
__device__ __forceinline__ float softplusf_(float x){ return fmaxf(x,0.f)+log1pf(__expf(-fabsf(x))); }
__device__ __forceinline__ float tanhf_(float x){ return 2.f*sigmoidf_(2.f*x)-1.f; }

// ---------------- setup kernels (once per call) ----------------

// Collapse ee-layer2 + attention-layer1(ef half) into fp16 hi/lo MFMA B-fragments (for edge kernel).
__global__ void __launch_bounds__(256) k_prep(
    const float* __restrict__ ee_w2, const float* __restrict__ ee_b2,
    const float* __restrict__ at_w1, const float* __restrict__ at_b1,
    _Float16* __restrict__ P_Mhi, _Float16* __restrict__ P_Mlo,
    float* __restrict__ cvec)
{
    int i = blockIdx.x*256 + threadIdx.x;   // 0..4095
    if (i >= 64*64) return;
    int m = i>>6, j = i&63;                 // m = K index, j = output col
    float acc = 0.f;
    #pragma unroll 8
    for (int k=0;k<64;++k) acc += ee_w2[k*64+m]*at_w1[j*128+k];
    int ks = m>>5;
    int lane = ((m>>3)&3)*16 + (j&15);
    int elem = m&7;
    int fi = (j>>4)*2 + ks;
    _Float16 hi = (_Float16)acc;
    P_Mhi[(fi*64+lane)*8+elem] = hi;
    P_Mlo[(fi*64+lane)*8+elem] = (_Float16)(acc - (float)hi);
    if (m == 0){
        float c = at_b1[j];
        #pragma unroll 8
        for (int k=0;k<64;++k) c += ee_b2[k]*at_w1[j*128+k];
        cvec[j] = c;
    }
}

// Generic B-fragment packer: B[k][j] taken from W[j*ldw + koff + k], zero for k>=K.
__device__ __forceinline__ void packB(const float* __restrict__ W, int ldw, int koff, int K, int NKS,
                                      _Float16* __restrict__ Dhi, _Float16* __restrict__ Dlo, int li){
    int elem = li & 7;
    int lane = (li >> 3) & 63;
    int fi   = li >> 9;
    int jt = fi / NKS, ks = fi % NKS;
    int j = jt*16 + (lane & 15);
    int k = ks*32 + ((lane>>4)&3)*8 + elem;
    float v = (k < K) ? W[j*ldw + koff + k] : 0.f;
    _Float16 hi = (_Float16)v;
    Dhi[li] = hi;
    Dlo[li] = (_Float16)(v - (float)hi);
}

// init state + pack node-update weights into MFMA B-fragments
__global__ void __launch_bounds__(256) k_init(
    const float* __restrict__ init_lice, const float* __restrict__ cvec,
    const float* __restrict__ en_w1, const float* __restrict__ en_w2,
    const float* __restrict__ gru_wih, const float* __restrict__ gru_whh,
    const float* __restrict__ de_w1, const float* __restrict__ at_w1,
    float* __restrict__ h, float* __restrict__ lice, float* __restrict__ G,
    _Float16* __restrict__ F_en1h, _Float16* __restrict__ F_en1l,
    _Float16* __restrict__ F_enh,  _Float16* __restrict__ F_enl,
    _Float16* __restrict__ F_ihh,  _Float16* __restrict__ F_ihl,
    _Float16* __restrict__ F_hhh,  _Float16* __restrict__ F_hhl,
    _Float16* __restrict__ F_deh,  _Float16* __restrict__ F_del,
    _Float16* __restrict__ F_a2h,  _Float16* __restrict__ F_a2l,
    int* __restrict__ counts)
{
    int i = blockIdx.x*256 + threadIdx.x;              // 0 .. 639999
    if (i < NNODES*HDIM){ h[i] = 0.f; G[i] = cvec[i&63]; }
    if (i < NNODES*LDIM) lice[i] = init_lice[i];
    if (i < NNODES) counts[i] = 0;
    if (i < 2048)       packB(en_w1,   5,  0,  5, 1, F_en1h, F_en1l, i);
    else if (i < 6144)  packB(en_w2,  64,  0, 64, 2, F_enh,  F_enl,  i-2048);
    else if (i < 24576) packB(gru_wih,72,  0, 72, 3, F_ihh,  F_ihl,  i-6144);
    else if (i < 36864) packB(gru_whh,64,  0, 64, 2, F_hhh,  F_hhl,  i-24576);
    else if (i < 40960) packB(de_w1,  64,  0, 64, 2, F_deh,  F_del,  i-36864);
    else if (i < 45056) packB(at_w1, 128, 64, 64, 2, F_a2h,  F_a2l,  i-40960);
}

// fec depends only on temp -> precompute for all (t,n)
__global__ void __launch_bounds__(256) k_fec(
    const float* __restrict__ nfs,
    const float* __restrict__ fe_w1, const float* __restrict__ fe_b1,
    const float* __restrict__ fe_w2, const float* __restrict__ fe_b2,
    const float* __restrict__ fe_w3, const float* __restrict__ fe_b3,
    float* __restrict__ fec_arr)
{
    int i = blockIdx.x*256 + threadIdx.x;
    if (i >= T_STEPS*NNODES) return;
    float temp = nfs[(size_t)i*NFEAT + 11];
    float tn = (temp - 10.f)*(1.f/5.f);
    float a[32];
    #pragma unroll
    for (int k=0;k<32;++k) a[k] = fmaxf(tn*fe_w1[k] + fe_b1[k], 0.f);
    float o = fe_b3[0];
    #pragma unroll 4
    for (int l=0;l<32;++l){
        float b = fe_b2[l];
        #pragma unroll
        for (int k=0;k<32;++k) b += a[k]*fe_w2[l*32+k];
        o += fmaxf(b, 0.f)*fe_w3[l];
    }
    fec_arr[i] = softplusf_(o);
}

__global__ void __launch_bounds__(256) k_hist(const int* __restrict__ ei_dst, int* __restrict__ counts){
    int e = blockIdx.x*256 + threadIdx.x;
    if (e < NEDGES) atomicAdd(&counts[ei_dst[e]], 1);
}

__global__ void __launch_bounds__(1024) k_scan(const int* __restrict__ counts,
                                               int* __restrict__ rowptr, int* __restrict__ cursor){
    __shared__ int sums[1024];
    int t = threadIdx.x;
    const int CH = 10;
    int c0 = t*CH;
    int s = 0;
    if (c0 < NNODES){
        #pragma unroll
        for (int i=0;i<CH;i++) s += counts[c0+i];
    }
    sums[t] = s;
    __syncthreads();
    for (int off=1; off<1024; off<<=1){
        int v = (t>=off) ? sums[t-off] : 0;
        __syncthreads();
        sums[t] += v;
        __syncthreads();
    }
    if (c0 < NNODES){
        int run = (t==0) ? 0 : sums[t-1];
        for (int i=0;i<CH;i++){ rowptr[c0+i] = run; run += counts[c0+i]; cursor[c0+i] = 0; }
        if (t == (NNODES/CH)-1) rowptr[NNODES] = run;
    }
}

__global__ void __launch_bounds__(256) k_scatter(const int* __restrict__ ei_dst,
        const int* __restrict__ rowptr, int* __restrict__ cursor, int* __restrict__ perm){
    int e = blockIdx.x*256 + threadIdx.x;
    if (e >= NEDGES) return;
    int d = ei_dst[e];
    int pos = rowptr[d] + atomicAdd(&cursor[d], 1);
    perm[pos] = e;
}

// pre-gather step-invariant per-edge data into CSR (perm) order
__global__ void __launch_bounds__(256) k_permg(
    const int* __restrict__ perm, const int* __restrict__ ei_src,
    const float* __restrict__ dist, const float* __restrict__ dirn,
    int* __restrict__ src_perm, float* __restrict__ dist_p, float* __restrict__ dirn_p)
{
    int i = blockIdx.x*256 + threadIdx.x;
    if (i >= NEDGES) return;
    int e = perm[i];
    src_perm[i] = ei_src[e];
    dist_p[i] = dist[e];
    float2 dd = *reinterpret_cast<const float2*>(dirn + 2*e);
    *reinterpret_cast<float2*>(dirn_p + 2*i) = dd;
}

// ---------------- per-step kernel 1: edge MLPs -> logits (MFMA fp16x3) ----------------

__global__ void __launch_bounds__(256,2) k_edge_mfma(
    const float* __restrict__ xt, const float* __restrict__ G,
    const int* __restrict__ src_perm,
    const float* __restrict__ dist_p, const float* __restrict__ dirn_p,
    const float* __restrict__ ee_w1, const float* __restrict__ ee_b1,
    const _Float16* __restrict__ P_Mhi, const _Float16* __restrict__ P_Mlo,
    const float* __restrict__ at_w2, const float* __restrict__ at_b2,
    float* __restrict__ logits)
{
    __shared__ __align__(16) _Float16 smh[36864];   // A_hi [256][72] | A_lo [256][72]; reused for C
    float* smf = (float*)smh;

    const int tid = threadIdx.x;
    const int wv = tid>>6, lane = tid&63;
    const int e = blockIdx.x*256 + tid;

    f16x8 bh[4][2], bl[4][2];
    #pragma unroll
    for (int jt=0;jt<4;++jt){
        #pragma unroll
        for (int ks=0;ks<2;++ks){
            bh[jt][ks] = *(const f16x8*)(P_Mhi + (((jt*2+ks)*64 + lane)*8));
            bl[jt][ks] = *(const f16x8*)(P_Mlo + (((jt*2+ks)*64 + lane)*8));
        }
    }

    const int src = src_perm[e];
    const float d  = dist_p[e];
    float2 dir2 = *reinterpret_cast<const float2*>(dirn_p + 2*e);
    float temp = xt[src*NFEAT+11];
    float4 q  = *reinterpret_cast<const float4*>(xt + src*NFEAT + 12);
    float flux = q.y*dir2.x + q.z*dir2.y;
    float wflux = fmaxf(flux, 0.f) * __expf(-d*(1.f/15.f));
    const float a0 = d, a1 = wflux, a2 = temp, a3 = q.x;
    const float lbias = at_b2[0] + __logf(wflux + 1e-8f);

    #pragma unroll
    for (int kb=0;kb<8;++kb){
        f16x8 hv, lv;
        #pragma unroll
        for (int i=0;i<8;++i){
            const int m = kb*8+i;
            float4 w1 = *reinterpret_cast<const float4*>(ee_w1 + m*4);
            float r = fmaxf(ee_b1[m] + a0*w1.x + a1*w1.y + a2*w1.z + a3*w1.w, 0.f);
            _Float16 hi = (_Float16)r;
            hv[i] = hi;
            lv[i] = (_Float16)(r - (float)hi);
        }
        *(f16x8*)(smh + tid*72 + kb*8)         = hv;
        *(f16x8*)(smh + 18432 + tid*72 + kb*8) = lv;
    }
    asm volatile("s_waitcnt lgkmcnt(0)" ::: "memory");

    f32x4 c[4][4];
    #pragma unroll
    for (int et=0;et<4;++et)
        #pragma unroll
        for (int jt=0;jt<4;++jt)
            c[et][jt] = (f32x4){0.f,0.f,0.f,0.f};

    #pragma unroll
    for (int et=0;et<4;++et){
        #pragma unroll
        for (int ks=0;ks<2;++ks){
            const int row = wv*64 + et*16 + (lane&15);
            f16x8 ah = *(const f16x8*)(smh + row*72 + ks*32 + (lane>>4)*8);
            f16x8 al = *(const f16x8*)(smh + 18432 + row*72 + ks*32 + (lane>>4)*8);
            #pragma unroll
            for (int jt=0;jt<4;++jt){
                c[et][jt] = __builtin_amdgcn_mfma_f32_16x16x32_f16(ah, bh[jt][ks], c[et][jt], 0,0,0);
                c[et][jt] = __builtin_amdgcn_mfma_f32_16x16x32_f16(ah, bl[jt][ks], c[et][jt], 0,0,0);
                c[et][jt] = __builtin_amdgcn_mfma_f32_16x16x32_f16(al, bh[jt][ks], c[et][jt], 0,0,0);
            }
        }
    }
    asm volatile("s_waitcnt lgkmcnt(0)" ::: "memory");

    #pragma unroll
    for (int et=0;et<4;++et){
        #pragma unroll
        for (int jt=0;jt<4;++jt){
            #pragma unroll
            for (int i=0;i<4;++i){
                const int rl = et*16 + ((lane>>4)&3)*4 + i;
                const int col = jt*16 + (lane&15);
                const int idx = (et < 2) ? (wv*2304 + rl*68 + col)
                                         : (9216 + wv*2304 + (rl-32)*68 + col);
                smf[idx] = c[et][jt][i];
            }
        }
    }
    asm volatile("s_waitcnt lgkmcnt(0)" ::: "memory");

    const int el = tid & 63;
    const float* crow = smf + ((el < 32) ? (wv*2304 + el*68)
                                         : (9216 + wv*2304 + (el-32)*68));
    const float4* G4 = reinterpret_cast<const float4*>(G + src*HDIM);
    float logit = lbias;
    #pragma unroll
    for (int jj=0;jj<16;++jj){
        float4 cv = *reinterpret_cast<const float4*>(crow + jj*4);
        float4 gv = G4[jj];
        float4 w4 = *reinterpret_cast<const float4*>(at_w2 + jj*4);
        logit += w4.x*fmaxf(cv.x+gv.x,0.f) + w4.y*fmaxf(cv.y+gv.y,0.f)
               + w4.z*fmaxf(cv.z+gv.z,0.f) + w4.w*fmaxf(cv.w+gv.w,0.f);
    }
    logits[e] = logit;
}

// ---------------- per-step kernel 2: segment softmax + pressure ----------------

__global__ void __launch_bounds__(256) k_softmax_pressure(
    const float* __restrict__ logits, const float* __restrict__ h,
    const float* __restrict__ lice, const int* __restrict__ src_perm,
    const int* __restrict__ rowptr,
    const float* __restrict__ log_beta,
    float* __restrict__ pressure)
{
    __shared__ float swgt[CAP];
    __shared__ int   ssrc[CAP];
    __shared__ float sred[4][64];
    __shared__ float sredm[4], sreds[4];

    const int node = blockIdx.x;
    const int tid = threadIdx.x;
    const int wid = tid >> 6;
    const int lane = tid & 63;
    const int start = rowptr[node], end = rowptr[node+1];
    const int deg = end - start;
    const int nfast = deg < CAP ? deg : CAP;

    float m = -INFINITY;
    for (int i=start+tid; i<end; i+=256){
        float lg = logits[i];
        int o = i - start;
        if (o < CAP){ swgt[o] = lg; ssrc[o] = src_perm[i]; }
        m = fmaxf(m, lg);
    }
    #pragma unroll
    for (int off=32; off>=1; off>>=1) m = fmaxf(m, __shfl_xor(m, off));
    if (lane == 0) sredm[wid] = m;
    __syncthreads();
    m = fmaxf(fmaxf(sredm[0], sredm[1]), fmaxf(sredm[2], sredm[3]));

    float s = 0.f;
    for (int i=start+tid; i<end; i+=256){
        int o = i - start;
        float lg = (o < CAP) ? swgt[o] : logits[i];
        s += __expf(lg - m);
    }
    #pragma unroll
    for (int off=32; off>=1; off>>=1) s += __shfl_xor(s, off);
    if (lane == 0) sreds[wid] = s;
    __syncthreads();
    s = (sreds[0]+sreds[1])+(sreds[2]+sreds[3]);

    const float binv = __expf(log_beta[0])/(s + 1e-8f);

    for (int o=tid; o<nfast; o+=256){
        int sc = ssrc[o];
        swgt[o] = __expf(swgt[o] - m) * binv * lice[sc*LDIM];
    }
    __syncthreads();

    float p = 0.f;
    for (int o=wid; o<nfast; o+=4)
        p += swgt[o]*h[ssrc[o]*HDIM + lane];
    for (int i=start+CAP+wid; i<end; i+=4){
        int sc = src_perm[i];
        float wg = __expf(logits[i]-m)*binv*lice[sc*LDIM];
        p += wg*h[sc*HDIM+lane];
    }
    sred[wid][lane] = p;
    __syncthreads();
    if (wid == 0)
        pressure[node*HDIM + lane] = (sred[0][lane]+sred[1][lane])+(sred[2][lane]+sred[3][lane]);
}

// ---------------- per-step kernel 3: node update via MFMA, 16-node tiles ----------------
// Block = 16 nodes, 256 threads = 4 waves, grid = 625 (exact). M=16 rows = nodes.
// Wave w owns col-tiles: enc/dec/G: jt=w; gates: jt in {w, 4+w, 8+w} -> in-register GRU glue.

__global__ void __launch_bounds__(256,4) k_node_mfma(
    const float* __restrict__ xt,
    float* __restrict__ h, float* __restrict__ lice,
    const float* __restrict__ pressure,
    const _Float16* __restrict__ F_en1h, const _Float16* __restrict__ F_en1l,
    const _Float16* __restrict__ F_enh,  const _Float16* __restrict__ F_enl,
    const _Float16* __restrict__ F_ihh,  const _Float16* __restrict__ F_ihl,
    const _Float16* __restrict__ F_hhh,  const _Float16* __restrict__ F_hhl,
    const _Float16* __restrict__ F_deh,  const _Float16* __restrict__ F_del,
    const _Float16* __restrict__ F_a2h,  const _Float16* __restrict__ F_a2l,
    const float* __restrict__ en_b1, const float* __restrict__ en_b2,
    const float* __restrict__ gru_bih, const float* __restrict__ gru_bhh,
    const float* __restrict__ de_b1, const float* __restrict__ de_w2, const float* __restrict__ de_b2,
    const float* __restrict__ cvec, const float* __restrict__ fec_t,
    const float* __restrict__ temp_sens,
    float* __restrict__ G, float* __restrict__ out_t)
{
    __shared__ __align__(16) _Float16 Ah_hi[16*72], Ah_lo[16*72];    // h tile, then hnew tile
    __shared__ __align__(16) _Float16 At_hi[16*72], At_lo[16*72];    // t1 (enc1 out)
    __shared__ __align__(16) _Float16 Ad_hi[16*104], Ad_lo[16*104];  // din tile (K=96 used)
    __shared__ float s_pd[16*64];                                    // pressure, then d1
    __shared__ float s_fec[16];

    const int tid = threadIdx.x;
    const int w = tid>>6, lane = tid&63;
    const int l15 = lane & 15, lq = (lane>>4)&3;
    const int n0 = blockIdx.x*16;

    // ---- phase 1: stage h (hi/lo), pressure, env/lice cols, fec ----
    {
        int node = tid>>4, k4 = tid&15;        // 256 threads = 16 nodes x 16 float4 slots
        int nc = n0 + node;
        float4 hv = *reinterpret_cast<const float4*>(h + nc*64 + k4*4);
        float4 pv = *reinterpret_cast<const float4*>(pressure + nc*64 + k4*4);
        *reinterpret_cast<float4*>(s_pd + node*64 + k4*4) = pv;
        f16x4 hh, hl;
        hh[0]=(_Float16)hv.x; hh[1]=(_Float16)hv.y; hh[2]=(_Float16)hv.z; hh[3]=(_Float16)hv.w;
        hl[0]=(_Float16)(hv.x-(float)hh[0]); hl[1]=(_Float16)(hv.y-(float)hh[1]);
        hl[2]=(_Float16)(hv.z-(float)hh[2]); hl[3]=(_Float16)(hv.w-(float)hh[3]);
        *reinterpret_cast<f16x4*>(Ah_hi + node*72 + k4*4) = hh;
        *reinterpret_cast<f16x4*>(Ah_lo + node*72 + k4*4) = hl;
    }
    if (w == 0 && lane < 16){
        int nc = n0 + lane;
        float ev[8];
        ev[0]=xt[nc*16+11]; ev[1]=xt[nc*16+12]; ev[2]=xt[nc*16+13];
        ev[3]=xt[nc*16+14]; ev[4]=xt[nc*16+15];
        ev[5]=lice[nc*3+0]; ev[6]=lice[nc*3+1]; ev[7]=lice[nc*3+2];
        s_fec[lane] = fec_t[nc];
        f16x8 eh, el;
        #pragma unroll
        for (int i=0;i<8;++i){ eh[i]=(_Float16)ev[i]; el[i]=(_Float16)(ev[i]-(float)eh[i]); }
        *reinterpret_cast<f16x8*>(Ad_hi + lane*104 + 64) = eh;
        *reinterpret_cast<f16x8*>(Ad_lo + lane*104 + 64) = el;
        f16x8 zz = {(_Float16)0,(_Float16)0,(_Float16)0,(_Float16)0,
                    (_Float16)0,(_Float16)0,(_Float16)0,(_Float16)0};
        *reinterpret_cast<f16x8*>(Ad_hi + lane*104 + 72) = zz;
        *reinterpret_cast<f16x8*>(Ad_hi + lane*104 + 80) = zz;
        *reinterpret_cast<f16x8*>(Ad_hi + lane*104 + 88) = zz;
        *reinterpret_cast<f16x8*>(Ad_lo + lane*104 + 72) = zz;
        *reinterpret_cast<f16x8*>(Ad_lo + lane*104 + 80) = zz;
        *reinterpret_cast<f16x8*>(Ad_lo + lane*104 + 88) = zz;
    }
    __syncthreads();

    // ---- phase 2a: enc1 (K=5 padded to 32; A = env/lice slice of Ad at k-offset 64) ----
    {
        f16x8 bh = *(const f16x8*)(F_en1h + (w*64+lane)*8);
        f16x8 bl = *(const f16x8*)(F_en1l + (w*64+lane)*8);
        f32x4 c = (f32x4){0.f,0.f,0.f,0.f};
        f16x8 ah = *(const f16x8*)(Ad_hi + l15*104 + 64 + lq*8);
        f16x8 al = *(const f16x8*)(Ad_lo + l15*104 + 64 + lq*8);
        c = __builtin_amdgcn_mfma_f32_16x16x32_f16(ah, bh, c,0,0,0);
        c = __builtin_amdgcn_mfma_f32_16x16x32_f16(ah, bl, c,0,0,0);
        c = __builtin_amdgcn_mfma_f32_16x16x32_f16(al, bh, c,0,0,0);
        int col = w*16 + l15;
        float b1 = en_b1[col];
        #pragma unroll
        for (int i=0;i<4;++i){
            int row = lq*4 + i;
            float v = fmaxf(c[i] + b1, 0.f);
            _Float16 hi = (_Float16)v;
            At_hi[row*72+col] = hi;
            At_lo[row*72+col] = (_Float16)(v-(float)hi);
        }
    }
    __syncthreads();

    // ---- phase 2b: enc2 + pressure -> din cols 0..63 ----
    {
        f32x4 c = (f32x4){0.f,0.f,0.f,0.f};
        #pragma unroll
        for (int ks=0; ks<2; ++ks){
            f16x8 bh = *(const f16x8*)(F_enh + ((w*2+ks)*64+lane)*8);
            f16x8 bl = *(const f16x8*)(F_enl + ((w*2+ks)*64+lane)*8);
            f16x8 ah = *(const f16x8*)(At_hi + l15*72 + ks*32 + lq*8);
            f16x8 al = *(const f16x8*)(At_lo + l15*72 + ks*32 + lq*8);
            c = __builtin_amdgcn_mfma_f32_16x16x32_f16(ah, bh, c,0,0,0);
            c = __builtin_amdgcn_mfma_f32_16x16x32_f16(ah, bl, c,0,0,0);
            c = __builtin_amdgcn_mfma_f32_16x16x32_f16(al, bh, c,0,0,0);
        }
        int col = w*16 + l15;
        float b2 = en_b2[col];
        #pragma unroll
        for (int i=0;i<4;++i){
            int row = lq*4 + i;
            float v = c[i] + b2 + s_pd[row*64+col];
            _Float16 hi = (_Float16)v;
            Ad_hi[row*104+col] = hi;
            Ad_lo[row*104+col] = (_Float16)(v-(float)hi);
        }
    }
    __syncthreads();

    // ---- phase 3: GRU gates. gates = din@Wih^T + h@Whh^T (+biases). ----
    f32x4 Cr, Cz, Ci, Chn;
    {
        int col = w*16 + l15;
        float br = gru_bih[col]     + gru_bhh[col];
        float bz = gru_bih[64+col]  + gru_bhh[64+col];
        float bi = gru_bih[128+col];
        float bn = gru_bhh[128+col];
        Cr  = (f32x4){br,br,br,br};
        Cz  = (f32x4){bz,bz,bz,bz};
        Ci  = (f32x4){bi,bi,bi,bi};
        Chn = (f32x4){bn,bn,bn,bn};
    }
    // din side: K=96 (3 ks); jt = w (r), 4+w (z), 8+w (n -> Ci)
    #pragma unroll
    for (int ks=0; ks<3; ++ks){
        f16x8 ah = *(const f16x8*)(Ad_hi + l15*104 + ks*32 + lq*8);
        f16x8 al = *(const f16x8*)(Ad_lo + l15*104 + ks*32 + lq*8);
        {
            int fi = w*3 + ks;
            f16x8 bh = *(const f16x8*)(F_ihh + (fi*64+lane)*8);
            f16x8 bl = *(const f16x8*)(F_ihl + (fi*64+lane)*8);
            Cr = __builtin_amdgcn_mfma_f32_16x16x32_f16(ah, bh, Cr,0,0,0);
            Cr = __builtin_amdgcn_mfma_f32_16x16x32_f16(ah, bl, Cr,0,0,0);
            Cr = __builtin_amdgcn_mfma_f32_16x16x32_f16(al, bh, Cr,0,0,0);
        }
        {
            int fi = (4+w)*3 + ks;
            f16x8 bh = *(const f16x8*)(F_ihh + (fi*64+lane)*8);
            f16x8 bl = *(const f16x8*)(F_ihl + (fi*64+lane)*8);
            Cz = __builtin_amdgcn_mfma_f32_16x16x32_f16(ah, bh, Cz,0,0,0);
            Cz = __builtin_amdgcn_mfma_f32_16x16x32_f16(ah, bl, Cz,0,0,0);
            Cz = __builtin_amdgcn_mfma_f32_16x16x32_f16(al, bh, Cz,0,0,0);
        }
        {
            int fi = (8+w)*3 + ks;
            f16x8 bh = *(const f16x8*)(F_ihh + (fi*64+lane)*8);
            f16x8 bl = *(const f16x8*)(F_ihl + (fi*64+lane)*8);
            Ci = __builtin_amdgcn_mfma_f32_16x16x32_f16(ah, bh, Ci,0,0,0);
            Ci = __builtin_amdgcn_mfma_f32_16x16x32_f16(ah, bl, Ci,0,0,0);
            Ci = __builtin_amdgcn_mfma_f32_16x16x32_f16(al, bh, Ci,0,0,0);
        }
    }
    // h side: K=64 (2 ks); jt = w (r), 4+w (z), 8+w (n -> Chn)
    #pragma unroll
    for (int ks=0; ks<2; ++ks){
        f16x8 ah = *(const f16x8*)(Ah_hi + l15*72 + ks*32 + lq*8);
        f16x8 al = *(const f16x8*)(Ah_lo + l15*72 + ks*32 + lq*8);
        {
            int fi = w*2 + ks;
            f16x8 bh = *(const f16x8*)(F_hhh + (fi*64+lane)*8);
            f16x8 bl = *(const f16x8*)(F_hhl + (fi*64+lane)*8);
            Cr = __builtin_amdgcn_mfma_f32_16x16x32_f16(ah, bh, Cr,0,0,0);
            Cr = __builtin_amdgcn_mfma_f32_16x16x32_f16(ah, bl, Cr,0,0,0);
            Cr = __builtin_amdgcn_mfma_f32_16x16x32_f16(al, bh, Cr,0,0,0);
        }
        {
            int fi = (4+w)*2 + ks;
            f16x8 bh = *(const f16x8*)(F_hhh + (fi*64+lane)*8);
            f16x8 bl = *(const f16x8*)(F_hhl + (fi*64+lane)*8);
            Cz = __builtin_amdgcn_mfma_f32_16x16x32_f16(ah, bh, Cz,0,0,0);
            Cz = __builtin_amdgcn_mfma_f32_16x16x32_f16(ah, bl, Cz,0,0,0);
            Cz = __builtin_amdgcn_mfma_f32_16x16x32_f16(al, bh, Cz,0,0,0);
        }
        {
            int fi = (8+w)*2 + ks;
            f16x8 bh = *(const f16x8*)(F_hhh + (fi*64+lane)*8);
            f16x8 bl = *(const f16x8*)(F_hhl + (fi*64+lane)*8);
            Chn = __builtin_amdgcn_mfma_f32_16x16x32_f16(ah, bh, Chn,0,0,0);
            Chn = __builtin_amdgcn_mfma_f32_16x16x32_f16(ah, bl, Chn,0,0,0);
            Chn = __builtin_amdgcn_mfma_f32_16x16x32_f16(al, bh, Chn,0,0,0);
        }
    }

    // ---- GRU glue fully in registers (hold = hi+lo reconstruction from Ah tile) ----
    float hnv[4];
    {
        const int coln = w*16 + l15;
        #pragma unroll
        for (int i=0;i<4;++i){
            int row = lq*4 + i;
            float r  = sigmoidf_(Cr[i]);
            float z  = sigmoidf_(Cz[i]);
            float nn = tanhf_(Ci[i] + r*Chn[i]);
            float hold = (float)Ah_hi[row*72+coln] + (float)Ah_lo[row*72+coln];
            hnv[i] = (1.f-z)*nn + z*hold;
        }
    }
    __syncthreads();                 // all waves done reading Ah/Ad tiles
    {
        const int coln = w*16 + l15;
        #pragma unroll
        for (int i=0;i<4;++i){
            int row = lq*4 + i;
            float v = hnv[i];
            h[(n0+row)*HDIM + coln] = v;
            _Float16 hi = (_Float16)v;
            Ah_hi[row*72+coln] = hi;
            Ah_lo[row*72+coln] = (_Float16)(v-(float)hi);
        }
    }
    __syncthreads();

    // ---- phase C: dec1 (relu -> s_pd) and G = cvec + hnew@A2 ----
    {
        int col = w*16 + l15;
        float bd = de_b1[col], bg = cvec[col];
        f32x4 Cd = (f32x4){bd,bd,bd,bd};
        f32x4 Cg = (f32x4){bg,bg,bg,bg};
        #pragma unroll
        for (int ks=0;ks<2;++ks){
            f16x8 ah = *(const f16x8*)(Ah_hi + l15*72 + ks*32 + lq*8);
            f16x8 al = *(const f16x8*)(Ah_lo + l15*72 + ks*32 + lq*8);
            f16x8 dh = *(const f16x8*)(F_deh + ((w*2+ks)*64+lane)*8);
            f16x8 dl = *(const f16x8*)(F_del + ((w*2+ks)*64+lane)*8);
            f16x8 gh = *(const f16x8*)(F_a2h + ((w*2+ks)*64+lane)*8);
            f16x8 gl = *(const f16x8*)(F_a2l + ((w*2+ks)*64+lane)*8);
            Cd = __builtin_amdgcn_mfma_f32_16x16x32_f16(ah, dh, Cd,0,0,0);
            Cd = __builtin_amdgcn_mfma_f32_16x16x32_f16(ah, dl, Cd,0,0,0);
            Cd = __builtin_amdgcn_mfma_f32_16x16x32_f16(al, dh, Cd,0,0,0);
            Cg = __builtin_amdgcn_mfma_f32_16x16x32_f16(ah, gh, Cg,0,0,0);
            Cg = __builtin_amdgcn_mfma_f32_16x16x32_f16(ah, gl, Cg,0,0,0);
            Cg = __builtin_amdgcn_mfma_f32_16x16x32_f16(al, gh, Cg,0,0,0);
        }
        #pragma unroll
        for (int i=0;i<4;++i){
            int row = lq*4 + i;
            G[(n0+row)*HDIM + col] = Cg[i];
            s_pd[row*64+col] = fmaxf(Cd[i], 0.f);
        }
    }
    __syncthreads();

    // ---- dec2: out = softplus(de_w2 @ d1 + b) * (1 + ts*(fec-1)) ----
    {
        float ts = temp_sens[0];
        #pragma unroll
        for (int m=0;m<4;++m){
            int node = w*4 + m;
            float d1v = s_pd[node*64 + lane];
            float s0 = d1v*de_w2[lane];
            float s1 = d1v*de_w2[64+lane];
            float s2 = d1v*de_w2[128+lane];
            #pragma unroll
            for (int off=32; off>=1; off>>=1){
                s0 += __shfl_xor(s0,off);
                s1 += __shfl_xor(s1,off);
                s2 += __shfl_xor(s2,off);
            }
            if (lane < LDIM){
                float fec = s_fec[node];
                float oi = (lane==0?s0:(lane==1?s1:s2)) + de_b2[lane];
                float lb = softplusf_(oi);
                float ln = lb*(1.f + ts*(fec-1.f));
                lice[(n0+node)*LDIM+lane] = ln;
                out_t[(n0+node)*LDIM+lane] = ln;
            }
        }
    }
}

// ---------------- launcher ----------------

extern "C" void kernel_launch(void* const* d_in, const int* in_sizes, int n_in,
                              void* d_out, int out_size, void* d_ws, size_t ws_size,
                              hipStream_t stream) {
    const float* nfs       = (const float*)d_in[0];
    const float* init_lice = (const float*)d_in[1];
    const float* dist      = (const float*)d_in[2];
    const float* dirn      = (const float*)d_in[3];
    const float* ee_w1     = (const float*)d_in[4];
    const float* ee_b1     = (const float*)d_in[5];
    const float* ee_w2     = (const float*)d_in[6];
    const float* ee_b2     = (const float*)d_in[7];
    const float* at_w1     = (const float*)d_in[8];
    const float* at_b1     = (const float*)d_in[9];
    const float* at_w2     = (const float*)d_in[10];
    const float* at_b2     = (const float*)d_in[11];
    const float* en_w1     = (const float*)d_in[12];
    const float* en_b1     = (const float*)d_in[13];
    const float* en_w2     = (const float*)d_in[14];
    const float* en_b2     = (const float*)d_in[15];
    const float* fe_w1     = (const float*)d_in[16];
    const float* fe_b1     = (const float*)d_in[17];
    const float* fe_w2     = (const float*)d_in[18];
    const float* fe_b2     = (const float*)d_in[19];
    const float* fe_w3     = (const float*)d_in[20];
    const float* fe_b3     = (const float*)d_in[21];
    const float* gru_wih   = (const float*)d_in[22];
    const float* gru_whh   = (const float*)d_in[23];
    const float* gru_bih   = (const float*)d_in[24];
    const float* gru_bhh   = (const float*)d_in[25];
    const float* de_w1     = (const float*)d_in[26];
    const float* de_b1     = (const float*)d_in[27];
    const float* de_w2     = (const float*)d_in[28];
    const float* de_b2     = (const float*)d_in[29];
    const float* log_beta  = (const float*)d_in[30];
    const float* temp_sens = (const float*)d_in[31];
    const int*   ei        = (const int*)d_in[32];
    const int*   ei_src = ei;
    const int*   ei_dst = ei + NEDGES;
    float* out = (float*)d_out;

    // workspace carve (floats; keep offsets %4 for 16B alignment)
    float* wsf = (float*)d_ws;
    size_t off = 0;
    float* h        = wsf + off; off += (size_t)NNODES*HDIM;
    float* lice     = wsf + off; off += (size_t)NNODES*LDIM + 2;
    off = (off + 3) & ~(size_t)3;
    float* logits   = wsf + off; off += (size_t)NEDGES;
    float* pressure = wsf + off; off += (size_t)NNODES*HDIM;
    float* G        = wsf + off; off += (size_t)NNODES*HDIM;
    float* cvec     = wsf + off; off += 64;
    _Float16* P_Mhi = (_Float16*)(wsf + off); off += 2048;     // 4096 halves
    _Float16* P_Mlo = (_Float16*)(wsf + off); off += 2048;
    _Float16* F_en1h= (_Float16*)(wsf + off); off += 1024;     // 2048 halves
    _Float16* F_en1l= (_Float16*)(wsf + off); off += 1024;
    _Float16* F_enh = (_Float16*)(wsf + off); off += 2048;     // 4096 halves
    _Float16* F_enl = (_Float16*)(wsf + off); off += 2048;
    _Float16* F_ihh = (_Float16*)(wsf + off); off += 9216;     // 18432 halves
    _Float16* F_ihl = (_Float16*)(wsf + off); off += 9216;
    _Float16* F_hhh = (_Float16*)(wsf + off); off += 6144;     // 12288 halves
    _Float16* F_hhl = (_Float16*)(wsf + off); off += 6144;
    _Float16* F_deh = (_Float16*)(wsf + off); off += 2048;
    _Float16* F_del = (_Float16*)(wsf + off); off += 2048;
    _Float16* F_a2h = (_Float16*)(wsf + off); off += 2048;
    _Float16* F_a2l = (_Float16*)(wsf + off); off += 2048;
    float* fec_arr  = wsf + off; off += (size_t)T_STEPS*NNODES;
    float* dist_p   = wsf + off; off += NEDGES;
    float* dirn_p   = wsf + off; off += 2*NEDGES;
    int* src_perm = (int*)(wsf + off); off += NEDGES;
    int* counts = (int*)(wsf + off); off += NNODES;
    int* rowptr = (int*)(wsf + off); off += NNODES+1;
    int* cursor = (int*)(wsf + off); off += NNODES;
    int* perm   = (int*)(wsf + off); off += NEDGES;

    // setup (k_prep first: k_init consumes cvec)
    k_prep<<<16,256,0,stream>>>(ee_w2, ee_b2, at_w1, at_b1, P_Mhi, P_Mlo, cvec);
    k_init<<<2500,256,0,stream>>>(init_lice, cvec,
                                  en_w1, en_w2, gru_wih, gru_whh, de_w1, at_w1,
                                  h, lice, G,
                                  F_en1h, F_en1l, F_enh, F_enl,
                                  F_ihh, F_ihl, F_hhh, F_hhl,
                                  F_deh, F_del, F_a2h, F_a2l,
                                  counts);
    k_fec<<<(T_STEPS*NNODES+255)/256,256,0,stream>>>(nfs, fe_w1, fe_b1, fe_w2, fe_b2,
                                                     fe_w3, fe_b3, fec_arr);
    k_hist<<<1250,256,0,stream>>>(ei_dst, counts);
    k_scan<<<1,1024,0,stream>>>(counts, rowptr, cursor);
    k_scatter<<<1250,256,0,stream>>>(ei_dst, rowptr, cursor, perm);
    k_permg<<<1250,256,0,stream>>>(perm, ei_src, dist, dirn, src_perm, dist_p, dirn_p);

    const int node_blocks = NNODES/16;   // 625 exact
    for (int t=0; t<T_STEPS; ++t){
        const float* xt = nfs + (size_t)t*NNODES*NFEAT;
        k_edge_mfma<<<1250,256,0,stream>>>(xt, G, src_perm, dist_p, dirn_p,
                                           ee_w1, ee_b1, P_Mhi, P_Mlo,
                                           at_w2, at_b2, logits);
        k_softmax_pressure<<<NNODES,256,0,stream>>>(logits, h, lice, src_perm,
                                                    rowptr, log_beta, pressure);
        k_node_mfma<<<node_blocks,256,0,stream>>>(xt, h, lice, pressure,
                                           F_en1h, F_en1l, F_enh, F_enl,
                                           F_ihh, F_ihl, F_hhh, F_hhl,
                                           F_deh, F_del, F_a2h, F_a2l,
                                           en_b1, en_b2, gru_bih, gru_bhh,
                                           de_b1, de_w2, de_b2,
                                           cvec, fec_arr + (size_t)t*NNODES,
                                           temp_sens,
                                           G, out + (size_t)t*NNODES*LDIM);
    }
}

// Round 12
// 738.460 us; speedup vs baseline: 1.4969x; 1.0246x over previous
//
#include <hip/hip_runtime.h>
#include <math.h>

#define T_STEPS 8
#define NNODES 10000
#define NFEAT 16
#define NEDGES 320000
#define HDIM 64
#define LDIM 3

typedef _Float16 f16x8 __attribute__((ext_vector_type(8)));
typedef _Float16 f16x4 __attribute__((ext_vector_type(4)));
typedef float f32x4 __attribute__((ext_vector_type(4)));

__device__ __forceinline__ float sigmoidf_(float x){ return 1.f/(1.f+__expf(-x)); }
__device__ __forceinline__ float softplusf_(float x){ return fmaxf(x,0.f)+log1pf(__expf(-fabsf(x))); }
__device__ __forceinline__ float tanhf_(float x){ return 2.f*sigmoidf_(2.f*x)-1.f; }

// ---------------- setup kernels (once per call) ----------------

// Collapse ee-layer2 + attention-layer1(ef half) into fp16 hi/lo MFMA B-fragments (edge kernel).
__global__ void __launch_bounds__(256) k_prep(
    const float* __restrict__ ee_w2, const float* __restrict__ ee_b2,
    const float* __restrict__ at_w1, const float* __restrict__ at_b1,
    _Float16* __restrict__ P_Mhi, _Float16* __restrict__ P_Mlo,
    float* __restrict__ cvec)
{
    int i = blockIdx.x*256 + threadIdx.x;   // 0..4095
    if (i >= 64*64) return;
    int m = i>>6, j = i&63;                 // m = K index, j = output col
    float acc = 0.f;
    #pragma unroll 8
    for (int k=0;k<64;++k) acc += ee_w2[k*64+m]*at_w1[j*128+k];
    int ks = m>>5;
    int lane = ((m>>3)&3)*16 + (j&15);
    int elem = m&7;
    int fi = (j>>4)*2 + ks;
    _Float16 hi = (_Float16)acc;
    P_Mhi[(fi*64+lane)*8+elem] = hi;
    P_Mlo[(fi*64+lane)*8+elem] = (_Float16)(acc - (float)hi);
    if (m == 0){
        float c = at_b1[j];
        #pragma unroll 8
        for (int k=0;k<64;++k) c += ee_b2[k]*at_w1[j*128+k];
        cvec[j] = c;
    }
}

// Generic B-fragment packer: B[k][j] taken from W[j*ldw + koff + k], zero for k>=K.
__device__ __forceinline__ void packB(const float* __restrict__ W, int ldw, int koff, int K, int NKS,
                                      _Float16* __restrict__ Dhi, _Float16* __restrict__ Dlo, int li){
    int elem = li & 7;
    int lane = (li >> 3) & 63;
    int fi   = li >> 9;
    int jt = fi / NKS, ks = fi % NKS;
    int j = jt*16 + (lane & 15);
    int k = ks*32 + ((lane>>4)&3)*8 + elem;
    float v = (k < K) ? W[j*ldw + koff + k] : 0.f;
    _Float16 hi = (_Float16)v;
    Dhi[li] = hi;
    Dlo[li] = (_Float16)(v - (float)hi);
}

// init state + pack node-update weights into MFMA B-fragments
__global__ void __launch_bounds__(256) k_init(
    const float* __restrict__ init_lice, const float* __restrict__ cvec,
    const float* __restrict__ en_w1, const float* __restrict__ en_w2,
    const float* __restrict__ gru_wih, const float* __restrict__ gru_whh,
    const float* __restrict__ de_w1, const float* __restrict__ at_w1,
    float* __restrict__ h, float* __restrict__ lice, float* __restrict__ G,
    _Float16* __restrict__ F_en1h, _Float16* __restrict__ F_en1l,
    _Float16* __restrict__ F_enh,  _Float16* __restrict__ F_enl,
    _Float16* __restrict__ F_ihh,  _Float16* __restrict__ F_ihl,
    _Float16* __restrict__ F_hhh,  _Float16* __restrict__ F_hhl,
    _Float16* __restrict__ F_deh,  _Float16* __restrict__ F_del,
    _Float16* __restrict__ F_a2h,  _Float16* __restrict__ F_a2l,
    int* __restrict__ counts)
{
    int i = blockIdx.x*256 + threadIdx.x;              // 0 .. 639999
    if (i < NNODES*HDIM){ h[i] = 0.f; G[i] = cvec[i&63]; }
    if (i < NNODES*LDIM) lice[i] = init_lice[i];
    if (i < NNODES) counts[i] = 0;
    if (i < 2048)       packB(en_w1,   5,  0,  5, 1, F_en1h, F_en1l, i);
    else if (i < 6144)  packB(en_w2,  64,  0, 64, 2, F_enh,  F_enl,  i-2048);
    else if (i < 24576) packB(gru_wih,72,  0, 72, 3, F_ihh,  F_ihl,  i-6144);
    else if (i < 36864) packB(gru_whh,64,  0, 64, 2, F_hhh,  F_hhl,  i-24576);
    else if (i < 40960) packB(de_w1,  64,  0, 64, 2, F_deh,  F_del,  i-36864);
    else if (i < 45056) packB(at_w1, 128, 64, 64, 2, F_a2h,  F_a2l,  i-40960);
}

// fec depends only on temp -> precompute for all (t,n)
__global__ void __launch_bounds__(256) k_fec(
    const float* __restrict__ nfs,
    const float* __restrict__ fe_w1, const float* __restrict__ fe_b1,
    const float* __restrict__ fe_w2, const float* __restrict__ fe_b2,
    const float* __restrict__ fe_w3, const float* __restrict__ fe_b3,
    float* __restrict__ fec_arr)
{
    int i = blockIdx.x*256 + threadIdx.x;
    if (i >= T_STEPS*NNODES) return;
    float temp = nfs[(size_t)i*NFEAT + 11];
    float tn = (temp - 10.f)*(1.f/5.f);
    float a[32];
    #pragma unroll
    for (int k=0;k<32;++k) a[k] = fmaxf(tn*fe_w1[k] + fe_b1[k], 0.f);
    float o = fe_b3[0];
    #pragma unroll 4
    for (int l=0;l<32;++l){
        float b = fe_b2[l];
        #pragma unroll
        for (int k=0;k<32;++k) b += a[k]*fe_w2[l*32+k];
        o += fmaxf(b, 0.f)*fe_w3[l];
    }
    fec_arr[i] = softplusf_(o);
}

__global__ void __launch_bounds__(256) k_hist(const int* __restrict__ ei_dst, int* __restrict__ counts){
    int e = blockIdx.x*256 + threadIdx.x;
    if (e < NEDGES) atomicAdd(&counts[ei_dst[e]], 1);
}

__global__ void __launch_bounds__(1024) k_scan(const int* __restrict__ counts,
                                               int* __restrict__ rowptr, int* __restrict__ cursor){
    __shared__ int sums[1024];
    int t = threadIdx.x;
    const int CH = 10;
    int c0 = t*CH;
    int s = 0;
    if (c0 < NNODES){
        #pragma unroll
        for (int i=0;i<CH;i++) s += counts[c0+i];
    }
    sums[t] = s;
    __syncthreads();
    for (int off=1; off<1024; off<<=1){
        int v = (t>=off) ? sums[t-off] : 0;
        __syncthreads();
        sums[t] += v;
        __syncthreads();
    }
    if (c0 < NNODES){
        int run = (t==0) ? 0 : sums[t-1];
        for (int i=0;i<CH;i++){ rowptr[c0+i] = run; run += counts[c0+i]; cursor[c0+i] = 0; }
        if (t == (NNODES/CH)-1) rowptr[NNODES] = run;
    }
}

// scatter + pre-gather step-invariant per-edge data into CSR order (permg merged)
__global__ void __launch_bounds__(256) k_scatter(
    const int* __restrict__ ei_src, const int* __restrict__ ei_dst,
    const int* __restrict__ rowptr, int* __restrict__ cursor,
    const float* __restrict__ dist, const float* __restrict__ dirn,
    int* __restrict__ src_perm, float* __restrict__ dist_p, float* __restrict__ dirn_p)
{
    int e = blockIdx.x*256 + threadIdx.x;
    if (e >= NEDGES) return;
    int d = ei_dst[e];
    int pos = rowptr[d] + atomicAdd(&cursor[d], 1);
    src_perm[pos] = ei_src[e];
    dist_p[pos] = dist[e];
    float2 dd = *reinterpret_cast<const float2*>(dirn + 2*e);
    *reinterpret_cast<float2*>(dirn_p + 2*pos) = dd;
}

// ---------------- per-step kernel 1: edge MLPs -> logits (MFMA fp16x3) ----------------

__global__ void __launch_bounds__(256,2) k_edge_mfma(
    const float* __restrict__ xt, const float* __restrict__ G,
    const int* __restrict__ src_perm,
    const float* __restrict__ dist_p, const float* __restrict__ dirn_p,
    const float* __restrict__ ee_w1, const float* __restrict__ ee_b1,
    const _Float16* __restrict__ P_Mhi, const _Float16* __restrict__ P_Mlo,
    const float* __restrict__ at_w2, const float* __restrict__ at_b2,
    float* __restrict__ logits)
{
    __shared__ __align__(16) _Float16 smh[36864];   // A_hi [256][72] | A_lo [256][72]; reused for C
    float* smf = (float*)smh;

    const int tid = threadIdx.x;
    const int wv = tid>>6, lane = tid&63;
    const int e = blockIdx.x*256 + tid;

    f16x8 bh[4][2], bl[4][2];
    #pragma unroll
    for (int jt=0;jt<4;++jt){
        #pragma unroll
        for (int ks=0;ks<2;++ks){
            bh[jt][ks] = *(const f16x8*)(P_Mhi + (((jt*2+ks)*64 + lane)*8));
            bl[jt][ks] = *(const f16x8*)(P_Mlo + (((jt*2+ks)*64 + lane)*8));
        }
    }

    const int src = src_perm[e];
    const float d  = dist_p[e];
    float2 dir2 = *reinterpret_cast<const float2*>(dirn_p + 2*e);
    float temp = xt[src*NFEAT+11];
    float4 q  = *reinterpret_cast<const float4*>(xt + src*NFEAT + 12);
    float flux = q.y*dir2.x + q.z*dir2.y;
    float wflux = fmaxf(flux, 0.f) * __expf(-d*(1.f/15.f));
    const float a0 = d, a1 = wflux, a2 = temp, a3 = q.x;
    const float lbias = at_b2[0] + __logf(wflux + 1e-8f);

    #pragma unroll
    for (int kb=0;kb<8;++kb){
        f16x8 hv, lv;
        #pragma unroll
        for (int i=0;i<8;++i){
            const int m = kb*8+i;
            float4 w1 = *reinterpret_cast<const float4*>(ee_w1 + m*4);
            float r = fmaxf(ee_b1[m] + a0*w1.x + a1*w1.y + a2*w1.z + a3*w1.w, 0.f);
            _Float16 hi = (_Float16)r;
            hv[i] = hi;
            lv[i] = (_Float16)(r - (float)hi);
        }
        *(f16x8*)(smh + tid*72 + kb*8)         = hv;
        *(f16x8*)(smh + 18432 + tid*72 + kb*8) = lv;
    }
    asm volatile("s_waitcnt lgkmcnt(0)" ::: "memory");

    f32x4 c[4][4];
    #pragma unroll
    for (int et=0;et<4;++et)
        #pragma unroll
        for (int jt=0;jt<4;++jt)
            c[et][jt] = (f32x4){0.f,0.f,0.f,0.f};

    #pragma unroll
    for (int et=0;et<4;++et){
        #pragma unroll
        for (int ks=0;ks<2;++ks){
            const int row = wv*64 + et*16 + (lane&15);
            f16x8 ah = *(const f16x8*)(smh + row*72 + ks*32 + (lane>>4)*8);
            f16x8 al = *(const f16x8*)(smh + 18432 + row*72 + ks*32 + (lane>>4)*8);
            #pragma unroll
            for (int jt=0;jt<4;++jt){
                c[et][jt] = __builtin_amdgcn_mfma_f32_16x16x32_f16(ah, bh[jt][ks], c[et][jt], 0,0,0);
                c[et][jt] = __builtin_amdgcn_mfma_f32_16x16x32_f16(ah, bl[jt][ks], c[et][jt], 0,0,0);
                c[et][jt] = __builtin_amdgcn_mfma_f32_16x16x32_f16(al, bh[jt][ks], c[et][jt], 0,0,0);
            }
        }
    }
    asm volatile("s_waitcnt lgkmcnt(0)" ::: "memory");

    #pragma unroll
    for (int et=0;et<4;++et){
        #pragma unroll
        for (int jt=0;jt<4;++jt){
            #pragma unroll
            for (int i=0;i<4;++i){
                const int rl = et*16 + ((lane>>4)&3)*4 + i;
                const int col = jt*16 + (lane&15);
                const int idx = (et < 2) ? (wv*2304 + rl*68 + col)
                                         : (9216 + wv*2304 + (rl-32)*68 + col);
                smf[idx] = c[et][jt][i];
            }
        }
    }
    asm volatile("s_waitcnt lgkmcnt(0)" ::: "memory");

    const int el = tid & 63;
    const float* crow = smf + ((el < 32) ? (wv*2304 + el*68)
                                         : (9216 + wv*2304 + (el-32)*68));
    const float4* G4 = reinterpret_cast<const float4*>(G + src*HDIM);
    float logit = lbias;
    #pragma unroll
    for (int jj=0;jj<16;++jj){
        float4 cv = *reinterpret_cast<const float4*>(crow + jj*4);
        float4 gv = G4[jj];
        float4 w4 = *reinterpret_cast<const float4*>(at_w2 + jj*4);
        logit += w4.x*fmaxf(cv.x+gv.x,0.f) + w4.y*fmaxf(cv.y+gv.y,0.f)
               + w4.z*fmaxf(cv.z+gv.z,0.f) + w4.w*fmaxf(cv.w+gv.w,0.f);
    }
    logits[e] = logit;
}

// ---------------- per-step kernel 2: FUSED softmax/pressure + node update (MFMA) ----------------
// Block = 16 nodes, 256 threads = 4 waves, grid = 625 exact.
// Phase A: wave w computes softmax+pressure for nodes w*4..w*4+3 (CSR-contiguous) -> s_pd.
// Then the verified 16-node MFMA pipeline (enc1, enc2, GRU, dec1/G, dec2).
// h/lice are double-buffered across steps (h_in read-only here; h_out written).

__global__ void __launch_bounds__(256,4) k_fused_node(
    const float* __restrict__ xt,
    const float* __restrict__ h_in, float* __restrict__ h_out,
    const float* __restrict__ lice_in, float* __restrict__ lice_out,
    const float* __restrict__ logits, const int* __restrict__ src_perm,
    const int* __restrict__ rowptr, const float* __restrict__ log_beta,
    const _Float16* __restrict__ F_en1h, const _Float16* __restrict__ F_en1l,
    const _Float16* __restrict__ F_enh,  const _Float16* __restrict__ F_enl,
    const _Float16* __restrict__ F_ihh,  const _Float16* __restrict__ F_ihl,
    const _Float16* __restrict__ F_hhh,  const _Float16* __restrict__ F_hhl,
    const _Float16* __restrict__ F_deh,  const _Float16* __restrict__ F_del,
    const _Float16* __restrict__ F_a2h,  const _Float16* __restrict__ F_a2l,
    const float* __restrict__ en_b1, const float* __restrict__ en_b2,
    const float* __restrict__ gru_bih, const float* __restrict__ gru_bhh,
    const float* __restrict__ de_b1, const float* __restrict__ de_w2, const float* __restrict__ de_b2,
    const float* __restrict__ cvec, const float* __restrict__ fec_t,
    const float* __restrict__ temp_sens,
    float* __restrict__ G, float* __restrict__ out_t)
{
    __shared__ __align__(16) _Float16 Ah_hi[16*72], Ah_lo[16*72];    // h tile, then hnew tile
    __shared__ __align__(16) _Float16 At_hi[16*72], At_lo[16*72];    // t1 (enc1 out)
    __shared__ __align__(16) _Float16 Ad_hi[16*104], Ad_lo[16*104];  // din tile (K=96 used)
    __shared__ float s_pd[16*64];                                    // pressure, then d1
    __shared__ float s_fec[16];

    const int tid = threadIdx.x;
    const int w = tid>>6, lane = tid&63;
    const int l15 = lane & 15, lq = (lane>>4)&3;
    const int n0 = blockIdx.x*16;

    // ---- phase 1: stage h_in (hi/lo), env/lice cols, fec ----
    {
        int node = tid>>4, k4 = tid&15;        // 256 threads = 16 nodes x 16 float4 slots
        int nc = n0 + node;
        float4 hv = *reinterpret_cast<const float4*>(h_in + nc*64 + k4*4);
        f16x4 hh, hl;
        hh[0]=(_Float16)hv.x; hh[1]=(_Float16)hv.y; hh[2]=(_Float16)hv.z; hh[3]=(_Float16)hv.w;
        hl[0]=(_Float16)(hv.x-(float)hh[0]); hl[1]=(_Float16)(hv.y-(float)hh[1]);
        hl[2]=(_Float16)(hv.z-(float)hh[2]); hl[3]=(_Float16)(hv.w-(float)hh[3]);
        *reinterpret_cast<f16x4*>(Ah_hi + node*72 + k4*4) = hh;
        *reinterpret_cast<f16x4*>(Ah_lo + node*72 + k4*4) = hl;
    }
    if (w == 0 && lane < 16){
        int nc = n0 + lane;
        float ev[8];
        ev[0]=xt[nc*16+11]; ev[1]=xt[nc*16+12]; ev[2]=xt[nc*16+13];
        ev[3]=xt[nc*16+14]; ev[4]=xt[nc*16+15];
        ev[5]=lice_in[nc*3+0]; ev[6]=lice_in[nc*3+1]; ev[7]=lice_in[nc*3+2];
        s_fec[lane] = fec_t[nc];
        f16x8 eh, el;
        #pragma unroll
        for (int i=0;i<8;++i){ eh[i]=(_Float16)ev[i]; el[i]=(_Float16)(ev[i]-(float)eh[i]); }
        *reinterpret_cast<f16x8*>(Ad_hi + lane*104 + 64) = eh;
        *reinterpret_cast<f16x8*>(Ad_lo + lane*104 + 64) = el;
        f16x8 zz = {(_Float16)0,(_Float16)0,(_Float16)0,(_Float16)0,
                    (_Float16)0,(_Float16)0,(_Float16)0,(_Float16)0};
        *reinterpret_cast<f16x8*>(Ad_hi + lane*104 + 72) = zz;
        *reinterpret_cast<f16x8*>(Ad_hi + lane*104 + 80) = zz;
        *reinterpret_cast<f16x8*>(Ad_hi + lane*104 + 88) = zz;
        *reinterpret_cast<f16x8*>(Ad_lo + lane*104 + 72) = zz;
        *reinterpret_cast<f16x8*>(Ad_lo + lane*104 + 80) = zz;
        *reinterpret_cast<f16x8*>(Ad_lo + lane*104 + 88) = zz;
    }

    // ---- phase A: softmax + pressure, wave w handles nodes w*4..w*4+3 ----
    {
        const float beta = __expf(log_beta[0]);
        #pragma unroll 1
        for (int k=0;k<4;++k){
            const int nn = w*4 + k;
            const int n = n0 + nn;
            const int s0 = rowptr[n], s1 = rowptr[n+1];

            float m = -INFINITY;
            for (int i=s0+lane; i<s1; i+=64) m = fmaxf(m, logits[i]);
            #pragma unroll
            for (int off=32; off>=1; off>>=1) m = fmaxf(m, __shfl_xor(m, off));

            float s = 0.f;
            for (int i=s0+lane; i<s1; i+=64) s += __expf(logits[i] - m);
            #pragma unroll
            for (int off=32; off>=1; off>>=1) s += __shfl_xor(s, off);

            const float binv = beta/(s + 1e-8f);

            float p0=0.f,p1=0.f,p2=0.f,p3=0.f;
            int i = s0;
            for (; i+4<=s1; i+=4){
                int a0=src_perm[i+0], a1=src_perm[i+1], a2=src_perm[i+2], a3=src_perm[i+3];
                float w0=__expf(logits[i+0]-m)*binv*lice_in[a0*LDIM];
                float w1=__expf(logits[i+1]-m)*binv*lice_in[a1*LDIM];
                float w2=__expf(logits[i+2]-m)*binv*lice_in[a2*LDIM];
                float w3=__expf(logits[i+3]-m)*binv*lice_in[a3*LDIM];
                p0 += w0*h_in[a0*HDIM+lane];
                p1 += w1*h_in[a1*HDIM+lane];
                p2 += w2*h_in[a2*HDIM+lane];
                p3 += w3*h_in[a3*HDIM+lane];
            }
            for (; i<s1; ++i){
                int a = src_perm[i];
                float wg = __expf(logits[i]-m)*binv*lice_in[a*LDIM];
                p0 += wg*h_in[a*HDIM+lane];
            }
            s_pd[nn*64 + lane] = (p0+p1)+(p2+p3);
        }
    }
    __syncthreads();

    // ---- phase 2a: enc1 (K=5 padded to 32; A = env/lice slice of Ad at k-offset 64) ----
    {
        f16x8 bh = *(const f16x8*)(F_en1h + (w*64+lane)*8);
        f16x8 bl = *(const f16x8*)(F_en1l + (w*64+lane)*8);
        f32x4 c = (f32x4){0.f,0.f,0.f,0.f};
        f16x8 ah = *(const f16x8*)(Ad_hi + l15*104 + 64 + lq*8);
        f16x8 al = *(const f16x8*)(Ad_lo + l15*104 + 64 + lq*8);
        c = __builtin_amdgcn_mfma_f32_16x16x32_f16(ah, bh, c,0,0,0);
        c = __builtin_amdgcn_mfma_f32_16x16x32_f16(ah, bl, c,0,0,0);
        c = __builtin_amdgcn_mfma_f32_16x16x32_f16(al, bh, c,0,0,0);
        int col = w*16 + l15;
        float b1 = en_b1[col];
        #pragma unroll
        for (int i=0;i<4;++i){
            int row = lq*4 + i;
            float v = fmaxf(c[i] + b1, 0.f);
            _Float16 hi = (_Float16)v;
            At_hi[row*72+col] = hi;
            At_lo[row*72+col] = (_Float16)(v-(float)hi);
        }
    }
    __syncthreads();

    // ---- phase 2b: enc2 + pressure -> din cols 0..63 ----
    {
        f32x4 c = (f32x4){0.f,0.f,0.f,0.f};
        #pragma unroll
        for (int ks=0; ks<2; ++ks){
            f16x8 bh = *(const f16x8*)(F_enh + ((w*2+ks)*64+lane)*8);
            f16x8 bl = *(const f16x8*)(F_enl + ((w*2+ks)*64+lane)*8);
            f16x8 ah = *(const f16x8*)(At_hi + l15*72 + ks*32 + lq*8);
            f16x8 al = *(const f16x8*)(At_lo + l15*72 + ks*32 + lq*8);
            c = __builtin_amdgcn_mfma_f32_16x16x32_f16(ah, bh, c,0,0,0);
            c = __builtin_amdgcn_mfma_f32_16x16x32_f16(ah, bl, c,0,0,0);
            c = __builtin_amdgcn_mfma_f32_16x16x32_f16(al, bh, c,0,0,0);
        }
        int col = w*16 + l15;
        float b2 = en_b2[col];
        #pragma unroll
        for (int i=0;i<4;++i){
            int row = lq*4 + i;
            float v = c[i] + b2 + s_pd[row*64+col];
            _Float16 hi = (_Float16)v;
            Ad_hi[row*104+col] = hi;
            Ad_lo[row*104+col] = (_Float16)(v-(float)hi);
        }
    }
    __syncthreads();

    // ---- phase 3: GRU gates. gates = din@Wih^T + h@Whh^T (+biases). ----
    f32x4 Cr, Cz, Ci, Chn;
    {
        int col = w*16 + l15;
        float br = gru_bih[col]     + gru_bhh[col];
        float bz = gru_bih[64+col]  + gru_bhh[64+col];
        float bi = gru_bih[128+col];
        float bn = gru_bhh[128+col];
        Cr  = (f32x4){br,br,br,br};
        Cz  = (f32x4){bz,bz,bz,bz};
        Ci  = (f32x4){bi,bi,bi,bi};
        Chn = (f32x4){bn,bn,bn,bn};
    }
    // din side: K=96 (3 ks); jt = w (r), 4+w (z), 8+w (n -> Ci)
    #pragma unroll
    for (int ks=0; ks<3; ++ks){
        f16x8 ah = *(const f16x8*)(Ad_hi + l15*104 + ks*32 + lq*8);
        f16x8 al = *(const f16x8*)(Ad_lo + l15*104 + ks*32 + lq*8);
        {
            int fi = w*3 + ks;
            f16x8 bh = *(const f16x8*)(F_ihh + (fi*64+lane)*8);
            f16x8 bl = *(const f16x8*)(F_ihl + (fi*64+lane)*8);
            Cr = __builtin_amdgcn_mfma_f32_16x16x32_f16(ah, bh, Cr,0,0,0);
            Cr = __builtin_amdgcn_mfma_f32_16x16x32_f16(ah, bl, Cr,0,0,0);
            Cr = __builtin_amdgcn_mfma_f32_16x16x32_f16(al, bh, Cr,0,0,0);
        }
        {
            int fi = (4+w)*3 + ks;
            f16x8 bh = *(const f16x8*)(F_ihh + (fi*64+lane)*8);
            f16x8 bl = *(const f16x8*)(F_ihl + (fi*64+lane)*8);
            Cz = __builtin_amdgcn_mfma_f32_16x16x32_f16(ah, bh, Cz,0,0,0);
            Cz = __builtin_amdgcn_mfma_f32_16x16x32_f16(ah, bl, Cz,0,0,0);
            Cz = __builtin_amdgcn_mfma_f32_16x16x32_f16(al, bh, Cz,0,0,0);
        }
        {
            int fi = (8+w)*3 + ks;
            f16x8 bh = *(const f16x8*)(F_ihh + (fi*64+lane)*8);
            f16x8 bl = *(const f16x8*)(F_ihl + (fi*64+lane)*8);
            Ci = __builtin_amdgcn_mfma_f32_16x16x32_f16(ah, bh, Ci,0,0,0);
            Ci = __builtin_amdgcn_mfma_f32_16x16x32_f16(ah, bl, Ci,0,0,0);
            Ci = __builtin_amdgcn_mfma_f32_16x16x32_f16(al, bh, Ci,0,0,0);
        }
    }
    // h side: K=64 (2 ks); jt = w (r), 4+w (z), 8+w (n -> Chn)
    #pragma unroll
    for (int ks=0; ks<2; ++ks){
        f16x8 ah = *(const f16x8*)(Ah_hi + l15*72 + ks*32 + lq*8);
        f16x8 al = *(const f16x8*)(Ah_lo + l15*72 + ks*32 + lq*8);
        {
            int fi = w*2 + ks;
            f16x8 bh = *(const f16x8*)(F_hhh + (fi*64+lane)*8);
            f16x8 bl = *(const f16x8*)(F_hhl + (fi*64+lane)*8);
            Cr = __builtin_amdgcn_mfma_f32_16x16x32_f16(ah, bh, Cr,0,0,0);
            Cr = __builtin_amdgcn_mfma_f32_16x16x32_f16(ah, bl, Cr,0,0,0);
            Cr = __builtin_amdgcn_mfma_f32_16x16x32_f16(al, bh, Cr,0,0,0);
        }
        {
            int fi = (4+w)*2 + ks;
            f16x8 bh = *(const f16x8*)(F_hhh + (fi*64+lane)*8);
            f16x8 bl = *(const f16x8*)(F_hhl + (fi*64+lane)*8);
            Cz = __builtin_amdgcn_mfma_f32_16x16x32_f16(ah, bh, Cz,0,0,0);
            Cz = __builtin_amdgcn_mfma_f32_16x16x32_f16(ah, bl, Cz,0,0,0);
            Cz = __builtin_amdgcn_mfma_f32_16x16x32_f16(al, bh, Cz,0,0,0);
        }
        {
            int fi = (8+w)*2 + ks;
            f16x8 bh = *(const f16x8*)(F_hhh + (fi*64+lane)*8);
            f16x8 bl = *(const f16x8*)(F_hhl + (fi*64+lane)*8);
            Chn = __builtin_amdgcn_mfma_f32_16x16x32_f16(ah, bh, Chn,0,0,0);
            Chn = __builtin_amdgcn_mfma_f32_16x16x32_f16(ah, bl, Chn,0,0,0);
            Chn = __builtin_amdgcn_mfma_f32_16x16x32_f16(al, bh, Chn,0,0,0);
        }
    }

    // ---- GRU glue fully in registers (hold = hi+lo reconstruction from Ah tile) ----
    float hnv[4];
    {
        const int coln = w*16 + l15;
        #pragma unroll
        for (int i=0;i<4;++i){
            int row = lq*4 + i;
            float r  = sigmoidf_(Cr[i]);
            float z  = sigmoidf_(Cz[i]);
            float nn = tanhf_(Ci[i] + r*Chn[i]);
            float hold = (float)Ah_hi[row*72+coln] + (float)Ah_lo[row*72+coln];
            hnv[i] = (1.f-z)*nn + z*hold;
        }
    }
    __syncthreads();                 // all waves done reading Ah/Ad tiles
    {
        const int coln = w*16 + l15;
        #pragma unroll
        for (int i=0;i<4;++i){
            int row = lq*4 + i;
            float v = hnv[i];
            h_out[(n0+row)*HDIM + coln] = v;
            _Float16 hi = (_Float16)v;
            Ah_hi[row*72+coln] = hi;
            Ah_lo[row*72+coln] = (_Float16)(v-(float)hi);
        }
    }
    __syncthreads();

    // ---- phase C: dec1 (relu -> s_pd) and G = cvec + hnew@A2 ----
    {
        int col = w*16 + l15;
        float bd = de_b1[col], bg = cvec[col];
        f32x4 Cd = (f32x4){bd,bd,bd,bd};
        f32x4 Cg = (f32x4){bg,bg,bg,bg};
        #pragma unroll
        for (int ks=0;ks<2;++ks){
            f16x8 ah = *(const f16x8*)(Ah_hi + l15*72 + ks*32 + lq*8);
            f16x8 al = *(const f16x8*)(Ah_lo + l15*72 + ks*32 + lq*8);
            f16x8 dh = *(const f16x8*)(F_deh + ((w*2+ks)*64+lane)*8);
            f16x8 dl = *(const f16x8*)(F_del + ((w*2+ks)*64+lane)*8);
            f16x8 gh = *(const f16x8*)(F_a2h + ((w*2+ks)*64+lane)*8);
            f16x8 gl = *(const f16x8*)(F_a2l + ((w*2+ks)*64+lane)*8);
            Cd = __builtin_amdgcn_mfma_f32_16x16x32_f16(ah, dh, Cd,0,0,0);
            Cd = __builtin_amdgcn_mfma_f32_16x16x32_f16(ah, dl, Cd,0,0,0);
            Cd = __builtin_amdgcn_mfma_f32_16x16x32_f16(al, dh, Cd,0,0,0);
            Cg = __builtin_amdgcn_mfma_f32_16x16x32_f16(ah, gh, Cg,0,0,0);
            Cg = __builtin_amdgcn_mfma_f32_16x16x32_f16(ah, gl, Cg,0,0,0);
            Cg = __builtin_amdgcn_mfma_f32_16x16x32_f16(al, gh, Cg,0,0,0);
        }
        #pragma unroll
        for (int i=0;i<4;++i){
            int row = lq*4 + i;
            G[(n0+row)*HDIM + col] = Cg[i];
            s_pd[row*64+col] = fmaxf(Cd[i], 0.f);
        }
    }
    __syncthreads();

    // ---- dec2: out = softplus(de_w2 @ d1 + b) * (1 + ts*(fec-1)) ----
    {
        float ts = temp_sens[0];
        #pragma unroll
        for (int m=0;m<4;++m){
            int node = w*4 + m;
            float d1v = s_pd[node*64 + lane];
            float s0 = d1v*de_w2[lane];
            float s1 = d1v*de_w2[64+lane];
            float s2 = d1v*de_w2[128+lane];
            #pragma unroll
            for (int off=32; off>=1; off>>=1){
                s0 += __shfl_xor(s0,off);
                s1 += __shfl_xor(s1,off);
                s2 += __shfl_xor(s2,off);
            }
            if (lane < LDIM){
                float fec = s_fec[node];
                float oi = (lane==0?s0:(lane==1?s1:s2)) + de_b2[lane];
                float lb = softplusf_(oi);
                float ln = lb*(1.f + ts*(fec-1.f));
                lice_out[(n0+node)*LDIM+lane] = ln;
                out_t[(n0+node)*LDIM+lane] = ln;
            }
        }
    }
}

// ---------------- launcher ----------------

extern "C" void kernel_launch(void* const* d_in, const int* in_sizes, int n_in,
                              void* d_out, int out_size, void* d_ws, size_t ws_size,
                              hipStream_t stream) {
    const float* nfs       = (const float*)d_in[0];
    const float* init_lice = (const float*)d_in[1];
    const float* dist      = (const float*)d_in[2];
    const float* dirn      = (const float*)d_in[3];
    const float* ee_w1     = (const float*)d_in[4];
    const float* ee_b1     = (const float*)d_in[5];
    const float* ee_w2     = (const float*)d_in[6];
    const float* ee_b2     = (const float*)d_in[7];
    const float* at_w1     = (const float*)d_in[8];
    const float* at_b1     = (const float*)d_in[9];
    const float* at_w2     = (const float*)d_in[10];
    const float* at_b2     = (const float*)d_in[11];
    const float* en_w1     = (const float*)d_in[12];
    const float* en_b1     = (const float*)d_in[13];
    const float* en_w2     = (const float*)d_in[14];
    const float* en_b2     = (const float*)d_in[15];
    const float* fe_w1     = (const float*)d_in[16];
    const float* fe_b1     = (const float*)d_in[17];
    const float* fe_w2     = (const float*)d_in[18];
    const float* fe_b2     = (const float*)d_in[19];
    const float* fe_w3     = (const float*)d_in[20];
    const float* fe_b3     = (const float*)d_in[21];
    const float* gru_wih   = (const float*)d_in[22];
    const float* gru_whh   = (const float*)d_in[23];
    const float* gru_bih   = (const float*)d_in[24];
    const float* gru_bhh   = (const float*)d_in[25];
    const float* de_w1     = (const float*)d_in[26];
    const float* de_b1     = (const float*)d_in[27];
    const float* de_w2     = (const float*)d_in[28];
    const float* de_b2     = (const float*)d_in[29];
    const float* log_beta  = (const float*)d_in[30];
    const float* temp_sens = (const float*)d_in[31];
    const int*   ei        = (const int*)d_in[32];
    const int*   ei_src = ei;
    const int*   ei_dst = ei + NEDGES;
    float* out = (float*)d_out;

    // workspace carve (floats; keep offsets %4 for 16B alignment)
    float* wsf = (float*)d_ws;
    size_t off = 0;
    float* h0       = wsf + off; off += (size_t)NNODES*HDIM;
    float* h1       = wsf + off; off += (size_t)NNODES*HDIM;
    float* lice0    = wsf + off; off += (size_t)NNODES*LDIM + 2;
    off = (off + 3) & ~(size_t)3;
    float* lice1    = wsf + off; off += (size_t)NNODES*LDIM + 2;
    off = (off + 3) & ~(size_t)3;
    float* logits   = wsf + off; off += (size_t)NEDGES;
    float* G        = wsf + off; off += (size_t)NNODES*HDIM;
    float* cvec     = wsf + off; off += 64;
    _Float16* P_Mhi = (_Float16*)(wsf + off); off += 2048;     // 4096 halves
    _Float16* P_Mlo = (_Float16*)(wsf + off); off += 2048;
    _Float16* F_en1h= (_Float16*)(wsf + off); off += 1024;     // 2048 halves
    _Float16* F_en1l= (_Float16*)(wsf + off); off += 1024;
    _Float16* F_enh = (_Float16*)(wsf + off); off += 2048;     // 4096 halves
    _Float16* F_enl = (_Float16*)(wsf + off); off += 2048;
    _Float16* F_ihh = (_Float16*)(wsf + off); off += 9216;     // 18432 halves
    _Float16* F_ihl = (_Float16*)(wsf + off); off += 9216;
    _Float16* F_hhh = (_Float16*)(wsf + off); off += 6144;     // 12288 halves
    _Float16* F_hhl = (_Float16*)(wsf + off); off += 6144;
    _Float16* F_deh = (_Float16*)(wsf + off); off += 2048;
    _Float16* F_del = (_Float16*)(wsf + off); off += 2048;
    _Float16* F_a2h = (_Float16*)(wsf + off); off += 2048;
    _Float16* F_a2l = (_Float16*)(wsf + off); off += 2048;
    float* fec_arr  = wsf + off; off += (size_t)T_STEPS*NNODES;
    float* dist_p   = wsf + off; off += NEDGES;
    float* dirn_p   = wsf + off; off += 2*NEDGES;
    int* src_perm = (int*)(wsf + off); off += NEDGES;
    int* counts = (int*)(wsf + off); off += NNODES;
    int* rowptr = (int*)(wsf + off); off += NNODES+1;
    int* cursor = (int*)(wsf + off); off += NNODES;

    // setup (k_prep first: k_init consumes cvec)
    k_prep<<<16,256,0,stream>>>(ee_w2, ee_b2, at_w1, at_b1, P_Mhi, P_Mlo, cvec);
    k_init<<<2500,256,0,stream>>>(init_lice, cvec,
                                  en_w1, en_w2, gru_wih, gru_whh, de_w1, at_w1,
                                  h0, lice0, G,
                                  F_en1h, F_en1l, F_enh, F_enl,
                                  F_ihh, F_ihl, F_hhh, F_hhl,
                                  F_deh, F_del, F_a2h, F_a2l,
                                  counts);
    k_fec<<<(T_STEPS*NNODES+255)/256,256,0,stream>>>(nfs, fe_w1, fe_b1, fe_w2, fe_b2,
                                                     fe_w3, fe_b3, fec_arr);
    k_hist<<<1250,256,0,stream>>>(ei_dst, counts);
    k_scan<<<1,1024,0,stream>>>(counts, rowptr, cursor);
    k_scatter<<<1250,256,0,stream>>>(ei_src, ei_dst, rowptr, cursor,
                                     dist, dirn, src_perm, dist_p, dirn_p);

    float* hbuf[2]    = {h0, h1};
    float* licebuf[2] = {lice0, lice1};
    const int node_blocks = NNODES/16;   // 625 exact
    for (int t=0; t<T_STEPS; ++t){
        const float* xt = nfs + (size_t)t*NNODES*NFEAT;
        float* h_in  = hbuf[t&1],    *h_out = hbuf[(t+1)&1];
        float* li_in = licebuf[t&1], *li_out = licebuf[(t+1)&1];
        k_edge_mfma<<<1250,256,0,stream>>>(xt, G, src_perm, dist_p, dirn_p,
                                           ee_w1, ee_b1, P_Mhi, P_Mlo,
                                           at_w2, at_b2, logits);
        k_fused_node<<<node_blocks,256,0,stream>>>(xt, h_in, h_out, li_in, li_out,
                                           logits, src_perm, rowptr, log_beta,
                                           F_en1h, F_en1l, F_enh, F_enl,
                                           F_ihh, F_ihl, F_hhh, F_hhl,
                                           F_deh, F_del, F_a2h, F_a2l,
                                           en_b1, en_b2, gru_bih, gru_bhh,
                                           de_b1, de_w2, de_b2,
                                           cvec, fec_arr + (size_t)t*NNODES,
                                           temp_sens,
                                           G, out + (size_t)t*NNODES*LDIM);
    }
}